// Round 2
// baseline (68.253 us; speedup 1.0000x reference)
//
#include <hip/hip_runtime.h>
#include <math.h>

#define NB   512
#define CIN  64
#define COUT 64
#define NV   25
#define NVP  28      // padded row (16B-aligned rows: 28*4 = 112 = 7*16)
#define MID  8
#define NINT 32

__device__ __forceinline__ float fast_rcp(float x) { return __builtin_amdgcn_rcpf(x); }
__device__ __forceinline__ float fast_tanh(float x) {
    float e = __expf(2.0f * x);
    return 1.0f - 2.0f * fast_rcp(e + 1.0f);
}
__device__ __forceinline__ float fast_sigmoid(float x) {
    return fast_rcp(1.0f + __expf(-x));
}

// 7-quad broadcast-row FMA: acc[0..24] += s * row[0..24] (row 16B-aligned, 28 floats)
#define QFMA(accv, rowptr, s) do {                                   \
    const float4* _rp = (const float4*)(rowptr);                     \
    _Pragma("unroll")                                                \
    for (int _j = 0; _j < 7; ++_j) {                                 \
        float4 _q = _rp[_j];                                         \
        accv[4*_j+0] += (s) * _q.x;                                  \
        if (4*_j+1 < 25) accv[4*_j+1] += (s) * _q.y;                 \
        if (4*_j+2 < 25) accv[4*_j+2] += (s) * _q.z;                 \
        if (4*_j+3 < 25) accv[4*_j+3] += (s) * _q.w;                 \
    }                                                                \
} while (0)

__global__ __launch_bounds__(256, 2)
void cga_fused(const float* __restrict__ x,
               const float* __restrict__ A_static,
               const float* __restrict__ w1, const float* __restrict__ b1,
               const float* __restrict__ w2, const float* __restrict__ b2,
               const float* __restrict__ w3, const float* __restrict__ b3,
               const float* __restrict__ diff_w, const float* __restrict__ diff_b,
               const float* __restrict__ edge_w, const float* __restrict__ edge_b,
               const float* __restrict__ att_w, const float* __restrict__ att_b,
               const float* __restrict__ cc1_w, const float* __restrict__ cc1_b,
               const float* __restrict__ bn_g, const float* __restrict__ bn_b,
               const float* __restrict__ bn_m, const float* __restrict__ bn_v,
               const float* __restrict__ cc2_w, const float* __restrict__ cc2_b,
               const float* __restrict__ cs_w, const float* __restrict__ cs_b,
               const float* __restrict__ alpha_p,
               float* __restrict__ out)
{
    const int b = blockIdx.x;
    const int t = threadIdx.x;
    const int c = t & 63;     // channel owned in the register-tile phases
    const int g = t >> 6;     // wave group 0..3

    __shared__ __align__(16) float xs [CIN * NVP];       // 1792  (padded rows for b128 broadcast)
    __shared__ __align__(16) float Ast[NV * NVP];        // 700   A_static transposed: Ast[v][u]
    __shared__ __align__(16) float x1s[MID * NV];        // 200
    __shared__ __align__(16) float x2s[MID * NV];        // 200
    __shared__ __align__(16) float x3s[COUT * NV];       // 1600  tight (odd stride -> conflict-free)
    __shared__ __align__(16) float Qs [MID * NV * NVP];  // 5600  Q[m][u][v-row]   (+ scratch reuse)
    __shared__ __align__(16) float Pt [MID * NV * NVP];  // 5600  P^T[m][v][u-row] (+ scratch reuse)
    __shared__ __align__(16) float xatt[COUT * NV];      // 1600
    __shared__ __align__(16) float gcnp[COUT * NV];      // 1600  gcn pre-catt
    __shared__ float catt[COUT];
    __shared__ float satt[NV + 7];

    const float alpha = alpha_p[0];
    const float* xb = x + (size_t)b * CIN * NV;

    // ===== Phase 0: stage x (padded rows) + A_static^T =====
    for (int i = t; i < CIN * NV; i += 256) {
        int cc = i / 25, v = i - cc * 25;
        xs[cc * NVP + v] = xb[i];
    }
    for (int i = t; i < NV * NV; i += 256) {
        int u = i / 25, v = i - u * 25;
        Ast[v * NVP + u] = A_static[i];
    }
    __syncthreads();

    // ===== Phase 1: x1, x2 (scalar) + x3 partial (k-split over 4 groups) =====
    for (int i = t; i < 2 * MID * NV; i += 256) {
        int which = (i >= MID * NV);
        int idx = i - which * (MID * NV);
        int m = idx / 25, v = idx - m * 25;
        const float* w = which ? w2 : w1;
        float acc = which ? b2[m] : b1[m];
        for (int k = 0; k < CIN; ++k) acc += w[m * 64 + k] * xs[k * NVP + v];
        if (which) x2s[idx] = acc; else x1s[idx] = acc;
    }
    {
        float acc[25];
        float bias = (g == 0) ? b3[c] : 0.0f;
        #pragma unroll
        for (int v = 0; v < 25; ++v) acc[v] = bias;
        const int k0 = g * 16;
        for (int k = k0; k < k0 + 16; ++k) {
            float wk = w3[c * 64 + k];
            QFMA(acc, &xs[k * NVP], wk);
        }
        __syncthreads();
        if (g) {
            float* sc = Qs + (g - 1) * 1600 + c * 25;
            #pragma unroll
            for (int v = 0; v < 25; ++v) sc[v] = acc[v];
        } else {
            float* xp = x3s + c * 25;
            #pragma unroll
            for (int v = 0; v < 25; ++v) xp[v] = acc[v];
        }
    }
    __syncthreads();
    for (int i = t; i < 1600; i += 256)
        x3s[i] += Qs[i] + Qs[1600 + i] + Qs[3200 + i];
    __syncthreads();

    // ===== Phase 2: Q[m][u][v], P^T[m][v][u] (fast tanh) =====
    for (int i = t; i < MID * NV * NV; i += 256) {
        int m = i / 625;
        int r = i - m * 625;
        int u = r / 25, v = r - u * 25;
        Qs[(m * 25 + u) * NVP + v] = fast_tanh(x1s[m * 25 + u] * x2s[m * 25 + v] * 0.2f);
        float dw0 = diff_w[2 * m], dw1 = diff_w[2 * m + 1];
        float a;
        if (m < 4) {
            int j0 = 2 * m, j1 = 2 * m + 1;
            a = dw0 * (x1s[j0 * 25 + u] - x2s[j0 * 25 + v])
              + dw1 * (x1s[j1 * 25 + u] - x2s[j1 * 25 + v]);
        } else {
            int j0 = 2 * m - 8, j1 = 2 * m - 7;
            a = dw0 * (x2s[j0 * 25 + u] - x1s[j0 * 25 + v])
              + dw1 * (x2s[j1 * 25 + u] - x1s[j1 * 25 + v]);
        }
        Pt[(m * 25 + v) * NVP + u] = fast_tanh(a + diff_b[m]);
    }
    __syncthreads();

    // per-thread row sum of x3 (needed for both bias terms)
    float s3 = 0.0f;
    for (int v = 0; v < 25; ++v) s3 += x3s[c * 25 + v];

    // ===== Phase A: x_att — m-split over 4 groups, acc[v] in regs =====
    {
        float acc[25];
        float ab = (g == 0) ? att_b[c] * s3 : 0.0f;
        #pragma unroll
        for (int v = 0; v < 25; ++v) acc[v] = ab;
        const float aw0 = att_w[c * 8 + 2 * g];
        const float aw1 = att_w[c * 8 + 2 * g + 1];
        #pragma unroll 1
        for (int mm = 0; mm < 2; ++mm) {
            const int m = 2 * g + mm;
            const float aw = mm ? aw1 : aw0;
            for (int u = 0; u < 25; ++u) {
                float s = aw * x3s[c * 25 + u];
                QFMA(acc, &Qs[(m * 25 + u) * NVP], s);
            }
        }
        __syncthreads();                       // all Q reads done -> Qs becomes scratch
        if (g) {
            float* sc = Qs + (g - 1) * 1600 + c * 25;
            #pragma unroll
            for (int v = 0; v < 25; ++v) sc[v] = acc[v];
        } else {
            float* xp = xatt + c * 25;
            #pragma unroll
            for (int v = 0; v < 25; ++v) xp[v] = acc[v];
        }
    }
    __syncthreads();
    for (int i = t; i < 1600; i += 256)
        xatt[i] += Qs[i] + Qs[1600 + i] + Qs[3200 + i];
    __syncthreads();

    // ===== Phase B: wave0 does the channel-MLP (shfl, no barriers); all do gcn =====
    if (t < 64) {
        float xm = 0.0f;
        for (int v = 0; v < 25; ++v) xm += xatt[t * 25 + v];
        xm *= 0.04f;
        float a1 = 0.0f;
        for (int ccq = 0; ccq < 64; ++ccq) {
            float xv = __shfl(xm, ccq, 64);
            if (t < NINT) a1 += cc1_w[t * 64 + ccq] * xv;
        }
        float h = 0.0f;
        if (t < NINT) {
            a1 += cc1_b[t];
            a1 = (a1 - bn_m[t]) * (bn_g[t] * rsqrtf(bn_v[t] + 1e-5f)) + bn_b[t];
            h = 0.5f * a1 * (1.0f + erff(a1 * 0.70710678118654752f));
        }
        float a2 = cc2_b[t];
        for (int i2 = 0; i2 < NINT; ++i2) {
            float hv = __shfl(h, i2, 64);
            a2 += cc2_w[t * 32 + i2] * hv;
        }
        catt[t] = fast_sigmoid(a2);
    }
    {
        float acc[25];
        float eb = (g == 0) ? alpha * edge_b[c] * s3 : 0.0f;
        #pragma unroll
        for (int v = 0; v < 25; ++v) acc[v] = eb;
        // static part: A_static^T rows, v-chunk per group ({0-6},{7-12+1}...: off 0/7/13/19)
        const int off = g * 6 + (g ? 1 : 0);
        const int L   = g ? 6 : 7;
        #pragma unroll 1
        for (int jv = 0; jv < 7; ++jv) {
            if (jv < L) {
                int v = off + jv;
                float s = x3s[c * 25 + v];
                QFMA(acc, &Ast[v * NVP], s);
            }
        }
        // dynamic part: m-split over groups
        const float ew0 = alpha * edge_w[c * 8 + 2 * g];
        const float ew1 = alpha * edge_w[c * 8 + 2 * g + 1];
        #pragma unroll 1
        for (int mm = 0; mm < 2; ++mm) {
            const int m = 2 * g + mm;
            const float ew = mm ? ew1 : ew0;
            for (int v = 0; v < 25; ++v) {
                float s = ew * x3s[c * 25 + v];
                QFMA(acc, &Pt[(m * 25 + v) * NVP], s);
            }
        }
        __syncthreads();                       // all Pt reads done -> Pt becomes scratch
        if (g) {
            float* sc = Pt + (g - 1) * 1600 + c * 25;
            #pragma unroll
            for (int v = 0; v < 25; ++v) sc[v] = acc[v];
        } else {
            float* gp = gcnp + c * 25;
            #pragma unroll
            for (int v = 0; v < 25; ++v) gp[v] = acc[v];
        }
    }
    __syncthreads();
    for (int i = t; i < 1600; i += 256)
        gcnp[i] += Pt[i] + Pt[1600 + i] + Pt[3200 + i];
    __syncthreads();

    // ===== spatial attention: 8 lanes per v, shfl-reduce =====
    if (t < 200) {
        int v = t >> 3, s = t & 7;
        float p = 0.0f;
        for (int k = 0; k < 8; ++k) {
            int cc = s + 8 * k;
            p += cs_w[cc] * gcnp[cc * 25 + v] * catt[cc];
        }
        p += __shfl_down(p, 4, 8);
        p += __shfl_down(p, 2, 8);
        p += __shfl_down(p, 1, 8);
        if (s == 0) satt[v] = fast_sigmoid(p + cs_b[0]);
    }
    __syncthreads();

    // ===== output: gcn*catt + xatt*satt + x =====
    float* ob = out + (size_t)b * COUT * NV;
    for (int i = t; i < 1600; i += 256) {
        int cc = i / 25, v = i - cc * 25;
        ob[i] = gcnp[i] * catt[cc] + xatt[i] * satt[v] + xs[cc * NVP + v];
    }
}

extern "C" void kernel_launch(void* const* d_in, const int* in_sizes, int n_in,
                              void* d_out, int out_size, void* d_ws, size_t ws_size,
                              hipStream_t stream) {
    const float* x        = (const float*)d_in[0];
    const float* A_static = (const float*)d_in[1];
    const float* w1       = (const float*)d_in[2];
    const float* b1       = (const float*)d_in[3];
    const float* w2       = (const float*)d_in[4];
    const float* b2       = (const float*)d_in[5];
    const float* w3       = (const float*)d_in[6];
    const float* b3       = (const float*)d_in[7];
    const float* diff_w   = (const float*)d_in[8];
    const float* diff_b   = (const float*)d_in[9];
    const float* edge_w   = (const float*)d_in[10];
    const float* edge_b   = (const float*)d_in[11];
    const float* att_w    = (const float*)d_in[12];
    const float* att_b    = (const float*)d_in[13];
    const float* cc1_w    = (const float*)d_in[14];
    const float* cc1_b    = (const float*)d_in[15];
    const float* bn_g     = (const float*)d_in[16];
    const float* bn_b     = (const float*)d_in[17];
    const float* bn_m     = (const float*)d_in[18];
    const float* bn_v     = (const float*)d_in[19];
    const float* cc2_w    = (const float*)d_in[20];
    const float* cc2_b    = (const float*)d_in[21];
    const float* cs_w     = (const float*)d_in[22];
    const float* cs_b     = (const float*)d_in[23];
    const float* alpha    = (const float*)d_in[24];
    float* outp = (float*)d_out;

    cga_fused<<<NB, 256, 0, stream>>>(x, A_static, w1, b1, w2, b2, w3, b3,
                                      diff_w, diff_b, edge_w, edge_b,
                                      att_w, att_b, cc1_w, cc1_b,
                                      bn_g, bn_b, bn_m, bn_v,
                                      cc2_w, cc2_b, cs_w, cs_b, alpha, outp);
}

// Round 3
// 48.999 us; speedup vs baseline: 1.3929x; 1.3929x over previous
//
#include <hip/hip_runtime.h>
#include <math.h>

#define NB   512
#define NVP  28      // Q/P/Ast padded row: 28*4B = 112B (16B-aligned rows)
#define XSP  32      // xs padded row

__device__ __forceinline__ float fast_rcp(float x) { return __builtin_amdgcn_rcpf(x); }
__device__ __forceinline__ float fast_tanh(float x) {
    float e = __expf(2.0f * x);
    return 1.0f - 2.0f * fast_rcp(e + 1.0f);
}
__device__ __forceinline__ float fast_sigmoid(float x) {
    return fast_rcp(1.0f + __expf(-x));
}

// compact 7x float4 FMA into aq[0..6]: aq += s * row[0..27] (row 16B aligned)
#define ROWFMA(aq, rowptr, s) do {                                    \
    const float4* _rp = (const float4*)(rowptr);                      \
    _Pragma("unroll")                                                 \
    for (int _j = 0; _j < 7; ++_j) {                                  \
        float4 _q = _rp[_j];                                          \
        aq[_j].x += (s) * _q.x;  aq[_j].y += (s) * _q.y;              \
        aq[_j].z += (s) * _q.z;  aq[_j].w += (s) * _q.w;              \
    }                                                                 \
} while (0)

__global__ __launch_bounds__(256, 2)
void cga_fused(const float* __restrict__ x,
               const float* __restrict__ A_static,
               const float* __restrict__ w1, const float* __restrict__ b1,
               const float* __restrict__ w2, const float* __restrict__ b2,
               const float* __restrict__ w3, const float* __restrict__ b3,
               const float* __restrict__ diff_w, const float* __restrict__ diff_b,
               const float* __restrict__ edge_w, const float* __restrict__ edge_b,
               const float* __restrict__ att_w, const float* __restrict__ att_b,
               const float* __restrict__ cc1_w, const float* __restrict__ cc1_b,
               const float* __restrict__ bn_g, const float* __restrict__ bn_b,
               const float* __restrict__ bn_m, const float* __restrict__ bn_v,
               const float* __restrict__ cc2_w, const float* __restrict__ cc2_b,
               const float* __restrict__ cs_w, const float* __restrict__ cs_b,
               const float* __restrict__ alpha_p,
               float* __restrict__ out)
{
    const int b = blockIdx.x;
    const int t = threadIdx.x;
    const int c = t & 63;   // channel lane
    const int g = t >> 6;   // wave 0..3

    __shared__ __align__(16) float xs [64 * XSP];      // 2048
    __shared__ __align__(16) float Ast[25 * NVP];      // 700  A^T rows: Ast[v][u..]
    __shared__ float x1s[200], x2s[200];
    __shared__ float x3s[64 * 25];                     // 1600
    __shared__ __align__(16) float Qs [8 * 25 * NVP];  // 5600 Q[m][u][v-row]; scratch later
    __shared__ __align__(16) float Pt [8 * 25 * NVP];  // 5600 P^T[m][v][u-row]; scratch later
    __shared__ float xatt[1600], gcnp[1600];
    __shared__ float catt[64], satt[25];

    const float alpha = alpha_p[0];
    const float* xb = x + (size_t)b * 1600;

    // ---- P0: stage x (pad cols zeroed) + A_static^T ----
    #pragma unroll 1
    for (int i = t; i < 64 * XSP; i += 256) {
        int cc = i >> 5, v = i & 31;
        xs[i] = (v < 25) ? xb[cc * 25 + v] : 0.0f;
    }
    #pragma unroll 1
    for (int i = t; i < 625; i += 256) {
        int u = i / 25, v = i - u * 25;
        Ast[v * NVP + u] = A_static[i];
    }
    __syncthreads();

    // ---- P1a: x1, x2 (scalar; 400 outputs) ----
    #pragma unroll 1
    for (int i = t; i < 400; i += 256) {
        int which = (i >= 200);
        int idx = i - 200 * which;
        int m = idx / 25, v = idx - m * 25;
        const float* w = which ? w2 : w1;
        float acc = which ? b2[m] : b1[m];
        #pragma unroll 4
        for (int k = 0; k < 64; ++k) acc += w[m * 64 + k] * xs[k * XSP + v];
        if (which) x2s[idx] = acc; else x1s[idx] = acc;
    }

    // ---- P1b: x3[c][v] — thread (c, v-octet), no reduction ----
    {
        const int vg = g * 8;
        float4 a0 = {0,0,0,0}, a1 = {0,0,0,0};
        const float bias = b3[c];
        #pragma unroll 2
        for (int k = 0; k < 64; ++k) {
            float wk = w3[c * 64 + k];
            const float4* xr = (const float4*)&xs[k * XSP + vg];
            float4 q0 = xr[0], q1 = xr[1];
            a0.x += wk * q0.x; a0.y += wk * q0.y; a0.z += wk * q0.z; a0.w += wk * q0.w;
            a1.x += wk * q1.x; a1.y += wk * q1.y; a1.z += wk * q1.z; a1.w += wk * q1.w;
        }
        float vv[8] = {a0.x, a0.y, a0.z, a0.w, a1.x, a1.y, a1.z, a1.w};
        #pragma unroll
        for (int j = 0; j < 8; ++j)
            if (vg + j < 25) x3s[c * 25 + vg + j] = vv[j] + bias;
    }
    __syncthreads();

    // ---- P2: Q[m][u][v] and P^T[m][v][u] ----
    #pragma unroll 1
    for (int i = t; i < 5000; i += 256) {
        int m = i / 625;
        int r = i - m * 625;
        int u = r / 25, v = r - u * 25;
        Qs[(m * 25 + u) * NVP + v] = fast_tanh(x1s[m * 25 + u] * x2s[m * 25 + v] * 0.2f);
        float dw0 = diff_w[2 * m], dw1 = diff_w[2 * m + 1];
        float a;
        if (m < 4) {
            int j0 = 2 * m, j1 = j0 + 1;
            a = dw0 * (x1s[j0 * 25 + u] - x2s[j0 * 25 + v])
              + dw1 * (x1s[j1 * 25 + u] - x2s[j1 * 25 + v]);
        } else {
            int j0 = 2 * m - 8, j1 = j0 + 1;
            a = dw0 * (x2s[j0 * 25 + u] - x1s[j0 * 25 + v])
              + dw1 * (x2s[j1 * 25 + u] - x1s[j1 * 25 + v]);
        }
        Pt[(m * 25 + v) * NVP + u] = fast_tanh(a + diff_b[m]);
    }
    __syncthreads();

    // s3 only needed by wave 0 (bias terms)
    float s3 = 0.0f;
    if (g == 0) {
        #pragma unroll 1
        for (int v = 0; v < 25; ++v) s3 += x3s[c * 25 + v];
    }

    // ---- Phase A: x_att, m-split (2 m per wave), lanes = c, acc in float4[7] ----
    {
        float4 aq[7];
        const float init = (g == 0) ? att_b[c] * s3 : 0.0f;
        #pragma unroll
        for (int j = 0; j < 7; ++j) { aq[j].x = init; aq[j].y = init; aq[j].z = init; aq[j].w = init; }
        #pragma unroll 1
        for (int mm = 0; mm < 2; ++mm) {
            const int m = 2 * g + mm;
            const float aw = att_w[c * 8 + m];
            #pragma unroll 1
            for (int u = 0; u < 25; ++u) {
                float s = aw * x3s[c * 25 + u];
                ROWFMA(aq, &Qs[(m * 25 + u) * NVP], s);
            }
        }
        __syncthreads();   // all Q reads done -> Qs is scratch
        float* dst = (g == 0) ? &xatt[c * 25] : &Qs[(g - 1) * 1600 + c * 25];
        #pragma unroll
        for (int j = 0; j < 7; ++j) {
            if (4*j+0 < 25) dst[4*j+0] = aq[j].x;
            if (4*j+1 < 25) dst[4*j+1] = aq[j].y;
            if (4*j+2 < 25) dst[4*j+2] = aq[j].z;
            if (4*j+3 < 25) dst[4*j+3] = aq[j].w;
        }
    }
    __syncthreads();
    #pragma unroll 1
    for (int i = t; i < 1600; i += 256)
        xatt[i] += Qs[i] + Qs[1600 + i] + Qs[3200 + i];
    __syncthreads();

    // ---- Phase B: gcn (dyn m-split) + A_static part on waves 1-3; MLP on wave 0 ----
    {
        float4 aq[7];
        const float init = (g == 0) ? alpha * edge_b[c] * s3 : 0.0f;
        #pragma unroll
        for (int j = 0; j < 7; ++j) { aq[j].x = init; aq[j].y = init; aq[j].z = init; aq[j].w = init; }

        if (g == 0) {
            // channel-MLP entirely in wave 0 via shfl (t == c here)
            float xm = 0.0f;
            #pragma unroll 1
            for (int v = 0; v < 25; ++v) xm += xatt[c * 25 + v];
            xm *= 0.04f;
            float a1 = 0.0f;
            #pragma unroll 1
            for (int q = 0; q < 64; ++q) {
                float xv = __shfl(xm, q, 64);
                float wq = (c < 32) ? cc1_w[c * 64 + q] : 0.0f;
                a1 += wq * xv;
            }
            float h = 0.0f;
            if (c < 32) {
                a1 += cc1_b[c];
                a1 = (a1 - bn_m[c]) * (bn_g[c] * rsqrtf(bn_v[c] + 1e-5f)) + bn_b[c];
                h = 0.5f * a1 * (1.0f + erff(a1 * 0.70710678118654752f));
            }
            float a2 = cc2_b[c];
            #pragma unroll 1
            for (int q2 = 0; q2 < 32; ++q2) {
                float hv = __shfl(h, q2, 64);
                a2 += cc2_w[c * 32 + q2] * hv;
            }
            catt[c] = fast_sigmoid(a2);
        } else {
            // static part: waves 1..3 cover v ranges 0-8 / 9-16 / 17-24
            const int v0 = (g == 1) ? 0 : (g == 2) ? 9 : 17;
            const int vn = (g == 1) ? 9 : 8;
            #pragma unroll 1
            for (int jv = 0; jv < vn; ++jv) {
                int v = v0 + jv;
                float s = x3s[c * 25 + v];
                ROWFMA(aq, &Ast[v * NVP], s);
            }
        }

        // dynamic part: m-split over all 4 waves
        #pragma unroll 1
        for (int mm = 0; mm < 2; ++mm) {
            const int m = 2 * g + mm;
            const float ew = alpha * edge_w[c * 8 + m];
            #pragma unroll 1
            for (int v = 0; v < 25; ++v) {
                float s = ew * x3s[c * 25 + v];
                ROWFMA(aq, &Pt[(m * 25 + v) * NVP], s);
            }
        }
        __syncthreads();   // all Pt reads done -> Pt is scratch
        float* dst = (g == 0) ? &gcnp[c * 25] : &Pt[(g - 1) * 1600 + c * 25];
        #pragma unroll
        for (int j = 0; j < 7; ++j) {
            if (4*j+0 < 25) dst[4*j+0] = aq[j].x;
            if (4*j+1 < 25) dst[4*j+1] = aq[j].y;
            if (4*j+2 < 25) dst[4*j+2] = aq[j].z;
            if (4*j+3 < 25) dst[4*j+3] = aq[j].w;
        }
    }
    __syncthreads();
    #pragma unroll 1
    for (int i = t; i < 1600; i += 256)
        gcnp[i] += Pt[i] + Pt[1600 + i] + Pt[3200 + i];
    __syncthreads();

    // ---- spatial attention: 8 lanes per v ----
    if (t < 200) {
        int v = t >> 3, s8 = t & 7;
        float p = 0.0f;
        #pragma unroll
        for (int k = 0; k < 8; ++k) {
            int cc = s8 + 8 * k;
            p += cs_w[cc] * gcnp[cc * 25 + v] * catt[cc];
        }
        p += __shfl_down(p, 4, 8);
        p += __shfl_down(p, 2, 8);
        p += __shfl_down(p, 1, 8);
        if (s8 == 0) satt[v] = fast_sigmoid(p + cs_b[0]);
    }
    __syncthreads();

    // ---- out = gcn*catt + xatt*satt + x ----
    float* ob = out + (size_t)b * 1600;
    #pragma unroll 1
    for (int i = t; i < 1600; i += 256) {
        int cc = i / 25, v = i - cc * 25;
        ob[i] = gcnp[i] * catt[cc] + xatt[i] * satt[v] + xs[cc * XSP + v];
    }
}

extern "C" void kernel_launch(void* const* d_in, const int* in_sizes, int n_in,
                              void* d_out, int out_size, void* d_ws, size_t ws_size,
                              hipStream_t stream) {
    const float* x        = (const float*)d_in[0];
    const float* A_static = (const float*)d_in[1];
    const float* w1       = (const float*)d_in[2];
    const float* b1       = (const float*)d_in[3];
    const float* w2       = (const float*)d_in[4];
    const float* b2       = (const float*)d_in[5];
    const float* w3       = (const float*)d_in[6];
    const float* b3       = (const float*)d_in[7];
    const float* diff_w   = (const float*)d_in[8];
    const float* diff_b   = (const float*)d_in[9];
    const float* edge_w   = (const float*)d_in[10];
    const float* edge_b   = (const float*)d_in[11];
    const float* att_w    = (const float*)d_in[12];
    const float* att_b    = (const float*)d_in[13];
    const float* cc1_w    = (const float*)d_in[14];
    const float* cc1_b    = (const float*)d_in[15];
    const float* bn_g     = (const float*)d_in[16];
    const float* bn_b     = (const float*)d_in[17];
    const float* bn_m     = (const float*)d_in[18];
    const float* bn_v     = (const float*)d_in[19];
    const float* cc2_w    = (const float*)d_in[20];
    const float* cc2_b    = (const float*)d_in[21];
    const float* cs_w     = (const float*)d_in[22];
    const float* cs_b     = (const float*)d_in[23];
    const float* alpha    = (const float*)d_in[24];
    float* outp = (float*)d_out;

    cga_fused<<<NB, 256, 0, stream>>>(x, A_static, w1, b1, w2, b2, w3, b3,
                                      diff_w, diff_b, edge_w, edge_b,
                                      att_w, att_b, cc1_w, cc1_b,
                                      bn_g, bn_b, bn_m, bn_v,
                                      cc2_w, cc2_b, cs_w, cs_b, alpha, outp);
}

// Round 6
// 37.342 us; speedup vs baseline: 1.8278x; 1.3122x over previous
//
#include <hip/hip_runtime.h>
#include <math.h>

#define NB   512
#define NVP  28      // padded row: 28*4B = 112B, 16B-aligned rows

__device__ __forceinline__ float fast_rcp(float x) { return __builtin_amdgcn_rcpf(x); }
__device__ __forceinline__ float fast_tanh(float x) {
    float e = __expf(2.0f * x);
    return 1.0f - 2.0f * fast_rcp(e + 1.0f);
}
__device__ __forceinline__ float fast_sigmoid(float x) {
    return fast_rcp(1.0f + __expf(-x));
}

__global__ __launch_bounds__(512, 4)
void cga_fused(const float* __restrict__ x,
               const float* __restrict__ A_static,
               const float* __restrict__ w1, const float* __restrict__ b1,
               const float* __restrict__ w2, const float* __restrict__ b2,
               const float* __restrict__ w3, const float* __restrict__ b3,
               const float* __restrict__ diff_w, const float* __restrict__ diff_b,
               const float* __restrict__ edge_w, const float* __restrict__ edge_b,
               const float* __restrict__ att_w, const float* __restrict__ att_b,
               const float* __restrict__ cc1_w, const float* __restrict__ cc1_b,
               const float* __restrict__ bn_g, const float* __restrict__ bn_b,
               const float* __restrict__ bn_m, const float* __restrict__ bn_v,
               const float* __restrict__ cc2_w, const float* __restrict__ cc2_b,
               const float* __restrict__ cs_w, const float* __restrict__ cs_b,
               const float* __restrict__ alpha_p,
               float* __restrict__ out)
{
    const int b = blockIdx.x;
    const int t = threadIdx.x;
    const int c = t & 63;   // lane = channel
    const int w = t >> 6;   // wave 0..7

    __shared__ __align__(16) float xs [64 * NVP];      // 1792
    __shared__ __align__(16) float Ast[25 * NVP];      // 700  Ast[v][u..] = A_static[u][v]
    __shared__ float x1s[200], x2s[200];
    __shared__ float x3s[64 * 25];                     // 1600
    __shared__ __align__(16) float Qs [8 * 25 * NVP];  // 5600 Q[m][u][v-row]; pre-P2: w3t
    __shared__ __align__(16) float Pt [8 * 25 * NVP];  // 5600 P^T[m][v][u-row]; pre-P2: w12t
    __shared__ float xatt[1600], gcnp[1600];
    __shared__ float catt[64], satt[32];

    float* const w3t  = Qs;   // [k*65 + c], 4160 <= 5600 (dead once P2 writes Q)
    float* const w12t = Pt;   // [k*17 + m'], 1088 <= 5600

    const float alpha = alpha_p[0];
    const float* xb = x + (size_t)b * 1600;

    // ===== stage: xs (padded), Ast (transposed), w3t, w12t =====
    #pragma unroll 1
    for (int i = t; i < 64 * NVP; i += 512) {
        int cc = i / NVP, v = i - cc * NVP;
        xs[i] = (v < 25) ? xb[cc * 25 + v] : 0.0f;
    }
    #pragma unroll 1
    for (int i = t; i < 625; i += 512) {
        int u = i / 25, v = i - u * 25;
        Ast[v * NVP + u] = A_static[i];
    }
    #pragma unroll 1
    for (int i = t; i < 4096; i += 512) {
        int cc = i >> 6, k = i & 63;
        w3t[k * 65 + cc] = w3[i];
    }
    #pragma unroll 1
    for (int i = t; i < 1024; i += 512) {          // grid-stride: stages BOTH w1 and w2
        int which = i >> 9, j = i & 511;
        int m = j >> 6, k = j & 63;
        w12t[k * 17 + m + 8 * which] = which ? w2[j] : w1[j];
    }
    __syncthreads();

    // ===== P1a: x1, x2 (400 outputs, threads t<400) =====
    if (t < 400) {
        int which = (t >= 200);
        int idx = t - 200 * which;
        int m = idx / 25, v = idx - m * 25;
        float acc = which ? b2[m] : b1[m];
        const int mo = m + 8 * which;
        #pragma unroll 4
        for (int k = 0; k < 64; ++k)
            acc += w12t[k * 17 + mo] * xs[k * NVP + v];
        if (which) x2s[idx] = acc; else x1s[idx] = acc;
    }
    // ===== P1b: x3, wave w owns v-quad w =====
    if (w < 7) {
        float4 a; a.x = a.y = a.z = a.w = 0.0f;
        #pragma unroll 2
        for (int k = 0; k < 64; ++k) {
            float wk = w3t[k * 65 + c];
            float4 xv = *(const float4*)&xs[k * NVP + 4 * w];
            a.x += wk * xv.x; a.y += wk * xv.y; a.z += wk * xv.z; a.w += wk * xv.w;
        }
        float bias = b3[c];
        #pragma unroll
        for (int j = 0; j < 4; ++j) {
            int v = 4 * w + j;
            if (v < 25) x3s[c * 25 + v] = (&a.x)[j] + bias;
        }
    }
    __syncthreads();

    // ===== P2: Q then P, each written stride-1 (conflict-free) =====
    #pragma unroll 1
    for (int i = t; i < 5000; i += 512) {
        int m = i / 625, r = i - m * 625;
        int u = r / 25, v = r - u * 25;
        Qs[(m * 25 + u) * NVP + v] = fast_tanh(x1s[m * 25 + u] * x2s[m * 25 + v] * 0.2f);
    }
    #pragma unroll 1
    for (int i = t; i < 5000; i += 512) {
        int m = i / 625, r = i - m * 625;
        int v = r / 25, u = r - v * 25;       // write P^T[m][v][u]
        float dw0 = diff_w[2 * m], dw1 = diff_w[2 * m + 1];
        float a;
        if (m < 4) {
            int j0 = 2 * m, j1 = j0 + 1;
            a = dw0 * (x1s[j0 * 25 + u] - x2s[j0 * 25 + v])
              + dw1 * (x1s[j1 * 25 + u] - x2s[j1 * 25 + v]);
        } else {
            int j0 = 2 * m - 8, j1 = j0 + 1;
            a = dw0 * (x2s[j0 * 25 + u] - x1s[j0 * 25 + v])
              + dw1 * (x2s[j1 * 25 + u] - x1s[j1 * 25 + v]);
        }
        Pt[(m * 25 + v) * NVP + u] = fast_tanh(a + diff_b[m]);
    }
    __syncthreads();

    // ===== combined A/B phase: 14 quad-tasks over 8 waves =====
    float s3 = 0.0f;
    #pragma unroll 1
    for (int v = 0; v < 25; ++v) s3 += x3s[c * 25 + v];

    #pragma unroll 1
    for (int pass = 0; pass < 2; ++pass) {
        const int tk = pass ? ((w < 6) ? w + 8 : 99) : w;
        if (tk < 7) {
            // ---- A-task: xatt[c][v-quad tk] ----
            const int q = tk;
            float4 aqm[8];
            #pragma unroll
            for (int m = 0; m < 8; ++m) { aqm[m].x = aqm[m].y = aqm[m].z = aqm[m].w = 0.0f; }
            #pragma unroll 1
            for (int u = 0; u < 25; ++u) {
                float x3v = x3s[c * 25 + u];
                const float* qb = &Qs[u * NVP + 4 * q];
                #pragma unroll
                for (int m = 0; m < 8; ++m) {
                    float4 qv = *(const float4*)(qb + m * (25 * NVP));
                    aqm[m].x += x3v * qv.x; aqm[m].y += x3v * qv.y;
                    aqm[m].z += x3v * qv.z; aqm[m].w += x3v * qv.w;
                }
            }
            const float4 a0 = *(const float4*)&att_w[c * 8];
            const float4 a1 = *(const float4*)&att_w[c * 8 + 4];
            float awv[8] = {a0.x, a0.y, a0.z, a0.w, a1.x, a1.y, a1.z, a1.w};
            float bias = att_b[c] * s3;
            float4 r; r.x = r.y = r.z = r.w = bias;
            #pragma unroll
            for (int m = 0; m < 8; ++m) {
                r.x += awv[m] * aqm[m].x; r.y += awv[m] * aqm[m].y;
                r.z += awv[m] * aqm[m].z; r.w += awv[m] * aqm[m].w;
            }
            #pragma unroll
            for (int j = 0; j < 4; ++j) {
                int v = 4 * q + j;
                if (v < 25) xatt[c * 25 + v] = (&r.x)[j];
            }
        } else if (tk < 14) {
            // ---- B-task: gcnp[c][u-quad tk-7] (pre-catt) ----
            const int q = tk - 7;
            float4 st; st.x = st.y = st.z = st.w = 0.0f;
            float4 aqm[8];
            #pragma unroll
            for (int m = 0; m < 8; ++m) { aqm[m].x = aqm[m].y = aqm[m].z = aqm[m].w = 0.0f; }
            #pragma unroll 1
            for (int v = 0; v < 25; ++v) {
                float x3v = x3s[c * 25 + v];
                float4 av = *(const float4*)&Ast[v * NVP + 4 * q];
                st.x += x3v * av.x; st.y += x3v * av.y;
                st.z += x3v * av.z; st.w += x3v * av.w;
                const float* pb = &Pt[v * NVP + 4 * q];
                #pragma unroll
                for (int m = 0; m < 8; ++m) {
                    float4 pv = *(const float4*)(pb + m * (25 * NVP));
                    aqm[m].x += x3v * pv.x; aqm[m].y += x3v * pv.y;
                    aqm[m].z += x3v * pv.z; aqm[m].w += x3v * pv.w;
                }
            }
            const float4 e0 = *(const float4*)&edge_w[c * 8];
            const float4 e1 = *(const float4*)&edge_w[c * 8 + 4];
            float ewv[8] = {e0.x, e0.y, e0.z, e0.w, e1.x, e1.y, e1.z, e1.w};
            float bias = alpha * edge_b[c] * s3;
            float4 r; r.x = st.x + bias; r.y = st.y + bias; r.z = st.z + bias; r.w = st.w + bias;
            #pragma unroll
            for (int m = 0; m < 8; ++m) {
                float ew = alpha * ewv[m];
                r.x += ew * aqm[m].x; r.y += ew * aqm[m].y;
                r.z += ew * aqm[m].z; r.w += ew * aqm[m].w;
            }
            #pragma unroll
            for (int j = 0; j < 4; ++j) {
                int u = 4 * q + j;
                if (u < 25) gcnp[c * 25 + u] = (&r.x)[j];
            }
        }
    }
    __syncthreads();

    // ===== MLP on wave 0 (t==c), shfl-based =====
    if (t < 64) {
        float xm = 0.0f;
        #pragma unroll 1
        for (int v = 0; v < 25; ++v) xm += xatt[c * 25 + v];
        xm *= 0.04f;
        float a1 = 0.0f;
        #pragma unroll 1
        for (int i4 = 0; i4 < 16; ++i4) {
            float4 wv; wv.x = wv.y = wv.z = wv.w = 0.0f;
            if (c < 32) wv = *(const float4*)&cc1_w[c * 64 + 4 * i4];
            a1 += wv.x * __shfl(xm, 4 * i4 + 0, 64);
            a1 += wv.y * __shfl(xm, 4 * i4 + 1, 64);
            a1 += wv.z * __shfl(xm, 4 * i4 + 2, 64);
            a1 += wv.w * __shfl(xm, 4 * i4 + 3, 64);
        }
        float h = 0.0f;
        if (c < 32) {
            a1 += cc1_b[c];
            a1 = (a1 - bn_m[c]) * (bn_g[c] * rsqrtf(bn_v[c] + 1e-5f)) + bn_b[c];
            h = 0.5f * a1 * (1.0f + erff(a1 * 0.70710678118654752f));
        }
        float a2 = cc2_b[c];
        #pragma unroll 1
        for (int i4 = 0; i4 < 8; ++i4) {
            float4 wv = *(const float4*)&cc2_w[c * 32 + 4 * i4];
            a2 += wv.x * __shfl(h, 4 * i4 + 0, 64);
            a2 += wv.y * __shfl(h, 4 * i4 + 1, 64);
            a2 += wv.z * __shfl(h, 4 * i4 + 2, 64);
            a2 += wv.w * __shfl(h, 4 * i4 + 3, 64);
        }
        catt[c] = fast_sigmoid(a2);
    }
    __syncthreads();

    // ===== spatial attention: 8 lanes per v =====
    if (t < 200) {
        int v = t >> 3, s8 = t & 7;
        float p = 0.0f;
        #pragma unroll
        for (int k = 0; k < 8; ++k) {
            int cc = s8 + 8 * k;
            p += cs_w[cc] * gcnp[cc * 25 + v] * catt[cc];
        }
        p += __shfl_down(p, 4, 8);
        p += __shfl_down(p, 2, 8);
        p += __shfl_down(p, 1, 8);
        if (s8 == 0) satt[v] = fast_sigmoid(p + cs_b[0]);
    }
    __syncthreads();

    // ===== out = gcn*catt + xatt*satt + x =====
    float* ob = out + (size_t)b * 1600;
    #pragma unroll 1
    for (int i = t; i < 1600; i += 512) {
        int cc = i / 25, v = i - cc * 25;
        ob[i] = gcnp[i] * catt[cc] + xatt[i] * satt[v] + xs[cc * NVP + v];
    }
}

extern "C" void kernel_launch(void* const* d_in, const int* in_sizes, int n_in,
                              void* d_out, int out_size, void* d_ws, size_t ws_size,
                              hipStream_t stream) {
    const float* x        = (const float*)d_in[0];
    const float* A_static = (const float*)d_in[1];
    const float* w1       = (const float*)d_in[2];
    const float* b1       = (const float*)d_in[3];
    const float* w2       = (const float*)d_in[4];
    const float* b2       = (const float*)d_in[5];
    const float* w3       = (const float*)d_in[6];
    const float* b3       = (const float*)d_in[7];
    const float* diff_w   = (const float*)d_in[8];
    const float* diff_b   = (const float*)d_in[9];
    const float* edge_w   = (const float*)d_in[10];
    const float* edge_b   = (const float*)d_in[11];
    const float* att_w    = (const float*)d_in[12];
    const float* att_b    = (const float*)d_in[13];
    const float* cc1_w    = (const float*)d_in[14];
    const float* cc1_b    = (const float*)d_in[15];
    const float* bn_g     = (const float*)d_in[16];
    const float* bn_b     = (const float*)d_in[17];
    const float* bn_m     = (const float*)d_in[18];
    const float* bn_v     = (const float*)d_in[19];
    const float* cc2_w    = (const float*)d_in[20];
    const float* cc2_b    = (const float*)d_in[21];
    const float* cs_w     = (const float*)d_in[22];
    const float* cs_b     = (const float*)d_in[23];
    const float* alpha    = (const float*)d_in[24];
    float* outp = (float*)d_out;

    cga_fused<<<NB, 512, 0, stream>>>(x, A_static, w1, b1, w2, b2, w3, b3,
                                      diff_w, diff_b, edge_w, edge_b,
                                      att_w, att_b, cc1_w, cc1_b,
                                      bn_g, bn_b, bn_m, bn_v,
                                      cc2_w, cc2_b, cs_w, cs_b, alpha, outp);
}

// Round 7
// 27.973 us; speedup vs baseline: 2.4400x; 1.3349x over previous
//
#include <hip/hip_runtime.h>
#include <math.h>

#define NB   512
#define NVP  28      // xs padded row

typedef __attribute__((ext_vector_type(8))) __bf16 bf16x8;
typedef __attribute__((ext_vector_type(4))) float  f32x4;

__device__ __forceinline__ float fast_rcp(float x) { return __builtin_amdgcn_rcpf(x); }
__device__ __forceinline__ float fast_tanh(float x) {
    float e = __expf(2.0f * x);
    return 1.0f - 2.0f * fast_rcp(e + 1.0f);
}
__device__ __forceinline__ float fast_sigmoid(float x) {
    return fast_rcp(1.0f + __expf(-x));
}
__device__ __forceinline__ unsigned pack_bf16(float a, float b) {
    unsigned short ux = __builtin_bit_cast(unsigned short, (__bf16)a);
    unsigned short uy = __builtin_bit_cast(unsigned short, (__bf16)b);
    return (unsigned)ux | ((unsigned)uy << 16);
}

__global__ __launch_bounds__(512, 4)
void cga_fused(const float* __restrict__ x,
               const float* __restrict__ A_static,
               const float* __restrict__ w1, const float* __restrict__ b1,
               const float* __restrict__ w2, const float* __restrict__ b2,
               const float* __restrict__ w3, const float* __restrict__ b3,
               const float* __restrict__ diff_w, const float* __restrict__ diff_b,
               const float* __restrict__ edge_w, const float* __restrict__ edge_b,
               const float* __restrict__ att_w, const float* __restrict__ att_b,
               const float* __restrict__ cc1_w, const float* __restrict__ cc1_b,
               const float* __restrict__ bn_g, const float* __restrict__ bn_b,
               const float* __restrict__ bn_m, const float* __restrict__ bn_v,
               const float* __restrict__ cc2_w, const float* __restrict__ cc2_b,
               const float* __restrict__ cs_w, const float* __restrict__ cs_b,
               const float* __restrict__ alpha_p,
               float* __restrict__ out)
{
    const int b = blockIdx.x;
    const int t = threadIdx.x;
    const int c = t & 63;   // lane
    const int w = t >> 6;   // wave 0..7

    // B-matrix bank for the batched GEMM: j=0..7 -> Q_m stored [v][u] (B[k=u][n=v]),
    // j=8..15 -> P_m stored [u][v] (B[k=v][n=u]), j=16 -> A_static [u][v].
    // Each j is 32x32 bf16, rows = n (64B), cols = k (contraction, pad 25..31 = 0).
    __shared__ __align__(16) __bf16 Bmats[17 * 32 * 32];   // 34816 B
    __shared__ __align__(16) __bf16 x3bf[64 * 32];         // 4096 B, A-operand (k-pad zeroed)
    __shared__ __align__(16) float xs [64 * NVP];          // 7168
    __shared__ float x1s[200], x2s[200];
    __shared__ float x3s[64 * 25];                         // 6400
    __shared__ float xatt[1600], gcnp[1600];               // 6400 each
    __shared__ float att_wT[8 * 64], edge_wT[8 * 64];      // 2048 each (edge pre-scaled by alpha)
    __shared__ float S3s[64];
    __shared__ float catt[64], satt[32];

    // staging-time aliases into the (then-dead) j<16 region of Bmats (8192 dwords)
    float* const w3t  = (float*)Bmats;          // [k*65 + c], 4160 floats
    float* const w12t = (float*)Bmats + 4160;   // [k*17 + m'], 1088 floats

    const float alpha = alpha_p[0];
    const float* xb = x + (size_t)b * 1600;

    // ===== stage: xs, w3t, w12t, att_wT, edge_wT, Ast -> Bmats[16] =====
    #pragma unroll 1
    for (int i = t; i < 64 * NVP; i += 512) {
        int cc = i / NVP, v = i - cc * NVP;
        xs[i] = (v < 25) ? xb[cc * 25 + v] : 0.0f;
    }
    #pragma unroll 1
    for (int i = t; i < 4096; i += 512) {
        int cc = i >> 6, k = i & 63;
        w3t[k * 65 + cc] = w3[i];
    }
    #pragma unroll 1
    for (int i = t; i < 1024; i += 512) {
        int which = i >> 9, j = i & 511;
        int m = j >> 6, k = j & 63;
        w12t[k * 17 + m + 8 * which] = which ? w2[j] : w1[j];
    }
    {   // att_wT[j][c], edge_wT[j][c] (alpha folded)
        int j = t >> 6;
        att_wT [j * 64 + c] = att_w [c * 8 + j];
        edge_wT[j * 64 + c] = alpha * edge_w[c * 8 + j];
    }
    {   // A_static -> Bmats[16][n=u][k=v], zero-padded to 32x32 (full coverage)
        int n = t >> 4, p = t & 15;
        int k0 = 2 * p, k1 = k0 + 1;
        float a0 = (n < 25 && k0 < 25) ? A_static[n * 25 + k0] : 0.0f;
        float a1 = (n < 25 && k1 < 25) ? A_static[n * 25 + k1] : 0.0f;
        ((unsigned*)Bmats)[16 * 512 + n * 16 + p] = pack_bf16(a0, a1);
    }
    __syncthreads();

    // ===== P1a: x1, x2 (t<400) =====
    if (t < 400) {
        int which = (t >= 200);
        int idx = t - 200 * which;
        int m = idx / 25, v = idx - m * 25;
        float acc = which ? b2[m] : b1[m];
        const int mo = m + 8 * which;
        #pragma unroll 4
        for (int k = 0; k < 64; ++k)
            acc += w12t[k * 17 + mo] * xs[k * NVP + v];
        if (which) x2s[idx] = acc; else x1s[idx] = acc;
    }
    // ===== P1b: x3, wave w owns v-quad w (w<7) =====
    if (w < 7) {
        float4 a; a.x = a.y = a.z = a.w = 0.0f;
        #pragma unroll 2
        for (int k = 0; k < 64; ++k) {
            float wk = w3t[k * 65 + c];
            float4 xv = *(const float4*)&xs[k * NVP + 4 * w];
            a.x += wk * xv.x; a.y += wk * xv.y; a.z += wk * xv.z; a.w += wk * xv.w;
        }
        float bias = b3[c];
        #pragma unroll
        for (int j = 0; j < 4; ++j) {
            int v = 4 * w + j;
            if (v < 25) x3s[c * 25 + v] = (&a.x)[j] + bias;
        }
    }
    __syncthreads();

    // ===== zero Bmats j<16 (w3t/w12t now dead), repack x3 -> bf16, S3 =====
    {
        unsigned* bz = (unsigned*)Bmats;
        #pragma unroll 1
        for (int i = t; i < 8192; i += 512) bz[i] = 0u;
    }
    #pragma unroll 1
    for (int i = t; i < 1024; i += 512) {
        int cc = i >> 4, p = i & 15;
        int k0 = 2 * p, k1 = k0 + 1;
        float f0 = (k0 < 25) ? x3s[cc * 25 + k0] : 0.0f;
        float f1 = (k1 < 25) ? x3s[cc * 25 + k1] : 0.0f;
        ((unsigned*)x3bf)[i] = pack_bf16(f0, f1);
    }
    if (t < 64) {
        float s = 0.0f;
        #pragma unroll 1
        for (int v = 0; v < 25; ++v) s += x3s[t * 25 + v];
        S3s[t] = s;
    }
    __syncthreads();

    // ===== P2: generate Q (j=m, [v][u]) and P (j=8+m, [u][v]) in bf16 =====
    #pragma unroll 1
    for (int i = t; i < 5000; i += 512) {
        int m = i / 625, r = i - m * 625;
        int v = r / 25, u = r - v * 25;   // contiguous u -> contiguous store
        float q = fast_tanh(x1s[m * 25 + u] * x2s[m * 25 + v] * 0.2f);
        Bmats[(m * 32 + v) * 32 + u] = (__bf16)q;
    }
    #pragma unroll 1
    for (int i = t; i < 5000; i += 512) {
        int m = i / 625, r = i - m * 625;
        int u = r / 25, v = r - u * 25;   // contiguous v -> contiguous store
        float dw0 = diff_w[2 * m], dw1 = diff_w[2 * m + 1];
        float a;
        if (m < 4) {
            int j0 = 2 * m, j1 = j0 + 1;
            a = dw0 * (x1s[j0 * 25 + u] - x2s[j0 * 25 + v])
              + dw1 * (x1s[j1 * 25 + u] - x2s[j1 * 25 + v]);
        } else {
            int j0 = 2 * m - 8, j1 = j0 + 1;
            a = dw0 * (x2s[j0 * 25 + u] - x1s[j0 * 25 + v])
              + dw1 * (x2s[j1 * 25 + u] - x1s[j1 * 25 + v]);
        }
        Bmats[((8 + m) * 32 + u) * 32 + v] = (__bf16)fast_tanh(a + diff_b[m]);
    }
    __syncthreads();

    // ===== MFMA phase: waves 0-3 -> xatt (j 0..7), waves 4-7 -> gcnp (j 8..16) =====
    {
        const int lane = c;
        const int ln = lane & 15, kq = lane >> 4;
        const int grp = w >> 2;          // 0 = A-phase, 1 = B-phase
        const int mt  = w & 3;           // M-tile (16 rows of c)
        const int arow = mt * 16 + ln;

        const bf16x8 araw = *(const bf16x8*)&x3bf[arow * 32 + kq * 8];
        float av[8];
        #pragma unroll
        for (int e = 0; e < 8; ++e) av[e] = (float)araw[e];

        f32x4 acc0 = {0.f, 0.f, 0.f, 0.f};
        f32x4 acc1 = {0.f, 0.f, 0.f, 0.f};
        const float* scT = grp ? edge_wT : att_wT;
        const int jbase = grp ? 8 : 0;

        #pragma unroll 1
        for (int j = 0; j < 8; ++j) {
            float sj = scT[j * 64 + arow];
            bf16x8 aj;
            #pragma unroll
            for (int e = 0; e < 8; ++e) aj[e] = (__bf16)(av[e] * sj);
            const __bf16* bb = &Bmats[(jbase + j) * 1024 + kq * 8];
            bf16x8 b0 = *(const bf16x8*)(bb + ln * 32);
            bf16x8 b1 = *(const bf16x8*)(bb + (16 + ln) * 32);
            acc0 = __builtin_amdgcn_mfma_f32_16x16x32_bf16(aj, b0, acc0, 0, 0, 0);
            acc1 = __builtin_amdgcn_mfma_f32_16x16x32_bf16(aj, b1, acc1, 0, 0, 0);
        }
        if (grp) {  // static A_static term, scale 1 (alpha NOT applied)
            const __bf16* bb = &Bmats[16 * 1024 + kq * 8];
            bf16x8 b0 = *(const bf16x8*)(bb + ln * 32);
            bf16x8 b1 = *(const bf16x8*)(bb + (16 + ln) * 32);
            acc0 = __builtin_amdgcn_mfma_f32_16x16x32_bf16(araw, b0, acc0, 0, 0, 0);
            acc1 = __builtin_amdgcn_mfma_f32_16x16x32_bf16(araw, b1, acc1, 0, 0, 0);
        }
        float* dstArr = grp ? gcnp : xatt;
        #pragma unroll
        for (int r = 0; r < 4; ++r) {
            int row = mt * 16 + kq * 4 + r;   // C layout: col=lane&15, row=(lane>>4)*4+reg
            float bias = grp ? (alpha * edge_b[row] * S3s[row])
                             : (att_b[row] * S3s[row]);
            dstArr[row * 25 + ln] = acc0[r] + bias;
            if (ln < 9) dstArr[row * 25 + 16 + ln] = acc1[r] + bias;
        }
    }
    __syncthreads();

    // ===== MLP on wave 0 (t==c), shfl-based =====
    if (t < 64) {
        float xm = 0.0f;
        #pragma unroll 1
        for (int v = 0; v < 25; ++v) xm += xatt[c * 25 + v];
        xm *= 0.04f;
        float a1 = 0.0f;
        #pragma unroll 1
        for (int i4 = 0; i4 < 16; ++i4) {
            float4 wv; wv.x = wv.y = wv.z = wv.w = 0.0f;
            if (c < 32) wv = *(const float4*)&cc1_w[c * 64 + 4 * i4];
            a1 += wv.x * __shfl(xm, 4 * i4 + 0, 64);
            a1 += wv.y * __shfl(xm, 4 * i4 + 1, 64);
            a1 += wv.z * __shfl(xm, 4 * i4 + 2, 64);
            a1 += wv.w * __shfl(xm, 4 * i4 + 3, 64);
        }
        float h = 0.0f;
        if (c < 32) {
            a1 += cc1_b[c];
            a1 = (a1 - bn_m[c]) * (bn_g[c] * rsqrtf(bn_v[c] + 1e-5f)) + bn_b[c];
            h = 0.5f * a1 * (1.0f + erff(a1 * 0.70710678118654752f));
        }
        float a2 = cc2_b[c];
        #pragma unroll 1
        for (int i4 = 0; i4 < 8; ++i4) {
            float4 wv = *(const float4*)&cc2_w[c * 32 + 4 * i4];
            a2 += wv.x * __shfl(h, 4 * i4 + 0, 64);
            a2 += wv.y * __shfl(h, 4 * i4 + 1, 64);
            a2 += wv.z * __shfl(h, 4 * i4 + 2, 64);
            a2 += wv.w * __shfl(h, 4 * i4 + 3, 64);
        }
        catt[c] = fast_sigmoid(a2);
    }
    __syncthreads();

    // ===== spatial attention: 8 lanes per v =====
    if (t < 200) {
        int v = t >> 3, s8 = t & 7;
        float p = 0.0f;
        #pragma unroll
        for (int k = 0; k < 8; ++k) {
            int cc = s8 + 8 * k;
            p += cs_w[cc] * gcnp[cc * 25 + v] * catt[cc];
        }
        p += __shfl_down(p, 4, 8);
        p += __shfl_down(p, 2, 8);
        p += __shfl_down(p, 1, 8);
        if (s8 == 0) satt[v] = fast_sigmoid(p + cs_b[0]);
    }
    __syncthreads();

    // ===== out = gcn*catt + xatt*satt + x =====
    float* ob = out + (size_t)b * 1600;
    #pragma unroll 1
    for (int i = t; i < 1600; i += 512) {
        int cc = i / 25, v = i - cc * 25;
        ob[i] = gcnp[i] * catt[cc] + xatt[i] * satt[v] + xs[cc * NVP + v];
    }
}

extern "C" void kernel_launch(void* const* d_in, const int* in_sizes, int n_in,
                              void* d_out, int out_size, void* d_ws, size_t ws_size,
                              hipStream_t stream) {
    const float* x        = (const float*)d_in[0];
    const float* A_static = (const float*)d_in[1];
    const float* w1       = (const float*)d_in[2];
    const float* b1       = (const float*)d_in[3];
    const float* w2       = (const float*)d_in[4];
    const float* b2       = (const float*)d_in[5];
    const float* w3       = (const float*)d_in[6];
    const float* b3       = (const float*)d_in[7];
    const float* diff_w   = (const float*)d_in[8];
    const float* diff_b   = (const float*)d_in[9];
    const float* edge_w   = (const float*)d_in[10];
    const float* edge_b   = (const float*)d_in[11];
    const float* att_w    = (const float*)d_in[12];
    const float* att_b    = (const float*)d_in[13];
    const float* cc1_w    = (const float*)d_in[14];
    const float* cc1_b    = (const float*)d_in[15];
    const float* bn_g     = (const float*)d_in[16];
    const float* bn_b     = (const float*)d_in[17];
    const float* bn_m     = (const float*)d_in[18];
    const float* bn_v     = (const float*)d_in[19];
    const float* cc2_w    = (const float*)d_in[20];
    const float* cc2_b    = (const float*)d_in[21];
    const float* cs_w     = (const float*)d_in[22];
    const float* cs_b     = (const float*)d_in[23];
    const float* alpha    = (const float*)d_in[24];
    float* outp = (float*)d_out;

    cga_fused<<<NB, 512, 0, stream>>>(x, A_static, w1, b1, w2, b2, w3, b3,
                                      diff_w, diff_b, edge_w, edge_b,
                                      att_w, att_b, cc1_w, cc1_b,
                                      bn_g, bn_b, bn_m, bn_v,
                                      cc2_w, cc2_b, cs_w, cs_b, alpha, outp);
}

// Round 9
// 25.650 us; speedup vs baseline: 2.6609x; 1.0906x over previous
//
#include <hip/hip_runtime.h>
#include <math.h>

#define NB   512

typedef __attribute__((ext_vector_type(8))) __bf16 bf16x8;
typedef __attribute__((ext_vector_type(4))) float  f32x4;

__device__ __forceinline__ float fast_rcp(float x) { return __builtin_amdgcn_rcpf(x); }
__device__ __forceinline__ float fast_tanh(float x) {
    float e = __expf(2.0f * x);
    return 1.0f - 2.0f * fast_rcp(e + 1.0f);
}
__device__ __forceinline__ float fast_sigmoid(float x) {
    return fast_rcp(1.0f + __expf(-x));
}
__device__ __forceinline__ unsigned pack_bf16(float a, float b) {
    unsigned short ux = __builtin_bit_cast(unsigned short, (__bf16)a);
    unsigned short uy = __builtin_bit_cast(unsigned short, (__bf16)b);
    return (unsigned)ux | ((unsigned)uy << 16);
}
__device__ __forceinline__ float bf16_res(float v) {   // v - bf16(v)
    return v - (float)(__bf16)v;
}

__global__ __launch_bounds__(512, 4)
void cga_fused(const float* __restrict__ x,
               const float* __restrict__ A_static,
               const float* __restrict__ w1, const float* __restrict__ b1,
               const float* __restrict__ w2, const float* __restrict__ b2,
               const float* __restrict__ w3, const float* __restrict__ b3,
               const float* __restrict__ diff_w, const float* __restrict__ diff_b,
               const float* __restrict__ edge_w, const float* __restrict__ edge_b,
               const float* __restrict__ att_w, const float* __restrict__ att_b,
               const float* __restrict__ cc1_w, const float* __restrict__ cc1_b,
               const float* __restrict__ bn_g, const float* __restrict__ bn_b,
               const float* __restrict__ bn_m, const float* __restrict__ bn_v,
               const float* __restrict__ cc2_w, const float* __restrict__ cc2_b,
               const float* __restrict__ cs_w, const float* __restrict__ cs_b,
               const float* __restrict__ alpha_p,
               float* __restrict__ out)
{
    const int b = blockIdx.x;
    const int t = threadIdx.x;
    const int c = t & 63;   // lane
    const int w = t >> 6;   // wave 0..7

    // Bmats: j=0..7 Q_m as B[n=v][k=u]; j=8..15 P_m as B[n=u][k=v]; j=16 A_static [n=u][k=v].
    // Before P2, the j<16 region aliases (bf16 elems):
    //   [0..5119]      wAbf hi  [80][64]  (rows 0-63 w3, 64-71 w1, 72-79 w2)
    //   [5120..10239]  wAbf lo  [80][64]
    //   [10240..12287] x lo     [32][64]
    // (A_static at elems 16384..17407 is untouched by staging/P2-j<16.)
    __shared__ __align__(16) __bf16 Bmats[17 * 32 * 32];   // 34816 B
    __shared__ __align__(16) __bf16 x3bf[64 * 32];         // A-operand of A/B phase [c][k=v]
    __shared__ __align__(16) __bf16 xsbf[32 * 64];         // x hi, B-operand of P1 [n=v][k=cin]
    __shared__ float x1s[200], x2s[200];
    __shared__ float x3s[64 * 25];
    __shared__ float xatt[1600], gcnp[1600];
    __shared__ float att_wT[512], edge_wT[512];            // [j][c], edge pre-scaled by alpha
    __shared__ float S3s[64], catt[64], satt[32];

    const float alpha = alpha_p[0];
    const float* xb = x + (size_t)b * 1600;

    // ===== stage: x (hi+lo), wA (hi+lo), att/edge_wT, A_static, zero x3bf =====
    {
        unsigned* xs32  = (unsigned*)xsbf;
        unsigned* xlo32 = (unsigned*)Bmats + 5120;
        #pragma unroll 1
        for (int i = t; i < 1024; i += 512) {
            int v = i >> 5, kp = i & 31;
            unsigned hi = 0u, lo = 0u;
            if (v < 25) {
                float f0 = xb[(2 * kp) * 25 + v], f1 = xb[(2 * kp + 1) * 25 + v];
                hi = pack_bf16(f0, f1);
                lo = pack_bf16(bf16_res(f0), bf16_res(f1));
            }
            xs32[i] = hi;
            xlo32[i] = lo;
        }
        unsigned* wA32  = (unsigned*)Bmats;
        unsigned* wAlo32 = wA32 + 2560;
        #pragma unroll 1
        for (int i = t; i < 2048; i += 512) {
            float2 wv = *(const float2*)&w3[2 * i];
            wA32[i]  = pack_bf16(wv.x, wv.y);
            wAlo32[i] = pack_bf16(bf16_res(wv.x), bf16_res(wv.y));
        }
        {   // w1 -> rows 64-71, w2 -> rows 72-79 (256 u32 each)
            int which = t >> 8, j = t & 255;
            const float* wsrc = which ? w2 : w1;
            float2 wv = *(const float2*)&wsrc[2 * j];
            wA32[2048 + t]  = pack_bf16(wv.x, wv.y);
            wAlo32[2048 + t] = pack_bf16(bf16_res(wv.x), bf16_res(wv.y));
        }
        unsigned* x3b32 = (unsigned*)x3bf;
        #pragma unroll 1
        for (int i = t; i < 1024; i += 512) x3b32[i] = 0u;
        {   // att_wT[j][c], edge_wT[j][c] (alpha folded)
            int j = t >> 6;
            att_wT [j * 64 + c] = att_w [c * 8 + j];
            edge_wT[j * 64 + c] = alpha * edge_w[c * 8 + j];
        }
        {   // A_static -> Bmats[16][n=u][k=v], zero-padded
            int n = t >> 4, p = t & 15;
            int k0 = 2 * p, k1 = k0 + 1;
            float a0 = (n < 25 && k0 < 25) ? A_static[n * 25 + k0] : 0.0f;
            float a1 = (n < 25 && k1 < 25) ? A_static[n * 25 + k1] : 0.0f;
            ((unsigned*)Bmats)[16 * 512 + n * 16 + p] = pack_bf16(a0, a1);
        }
    }
    __syncthreads();

    // ===== P1 (split-bf16 MFMA): [x3; x1; x2] = wA(80x64) @ x(64x25) =====
    // acc = wHi*xHi + wHi*xLo + wLo*xHi  (effectively fp32-accurate inputs)
    {
        const int ln = c & 15, kq = c >> 4;
        #pragma unroll 1
        for (int pass = 0; pass < 2; ++pass) {
            const int jb = pass ? (w + 8) : w;
            if (jb <= 9) {
                const int nt = (jb >= 5) ? 1 : 0;
                const int mt = jb - nt * 5;
                const int arow = mt * 16 + ln;
                const int brow = nt * 16 + ln;
                f32x4 acc = {0.f, 0.f, 0.f, 0.f};
                bf16x8 ah0 = *(const bf16x8*)&Bmats[arow * 64 + kq * 8];
                bf16x8 ah1 = *(const bf16x8*)&Bmats[arow * 64 + 32 + kq * 8];
                bf16x8 al0 = *(const bf16x8*)&Bmats[5120 + arow * 64 + kq * 8];
                bf16x8 al1 = *(const bf16x8*)&Bmats[5120 + arow * 64 + 32 + kq * 8];
                bf16x8 bh0 = *(const bf16x8*)&xsbf[brow * 64 + kq * 8];
                bf16x8 bh1 = *(const bf16x8*)&xsbf[brow * 64 + 32 + kq * 8];
                bf16x8 bl0 = *(const bf16x8*)&Bmats[10240 + brow * 64 + kq * 8];
                bf16x8 bl1 = *(const bf16x8*)&Bmats[10240 + brow * 64 + 32 + kq * 8];
                acc = __builtin_amdgcn_mfma_f32_16x16x32_bf16(ah0, bh0, acc, 0, 0, 0);
                acc = __builtin_amdgcn_mfma_f32_16x16x32_bf16(ah1, bh1, acc, 0, 0, 0);
                acc = __builtin_amdgcn_mfma_f32_16x16x32_bf16(ah0, bl0, acc, 0, 0, 0);
                acc = __builtin_amdgcn_mfma_f32_16x16x32_bf16(ah1, bl1, acc, 0, 0, 0);
                acc = __builtin_amdgcn_mfma_f32_16x16x32_bf16(al0, bh0, acc, 0, 0, 0);
                acc = __builtin_amdgcn_mfma_f32_16x16x32_bf16(al1, bh1, acc, 0, 0, 0);
                const int colv = nt * 16 + ln;
                if (colv < 25) {
                    if (mt < 4) {
                        #pragma unroll
                        for (int r = 0; r < 4; ++r) {
                            int cc = mt * 16 + kq * 4 + r;
                            float val = acc[r] + b3[cc];
                            x3s[cc * 25 + colv] = val;
                            x3bf[cc * 32 + colv] = (__bf16)val;
                        }
                    } else {
                        #pragma unroll
                        for (int r = 0; r < 4; ++r) {
                            int row16 = kq * 4 + r;
                            int which = row16 >> 3, m = row16 & 7;
                            float val = acc[r] + (which ? b2[m] : b1[m]);
                            (which ? x2s : x1s)[m * 25 + colv] = val;
                        }
                    }
                }
            }
        }
    }
    __syncthreads();

    // ===== P2: generate Q (j<8) / P (j>=8) incl. zero pads; S3 on t<64 =====
    #pragma unroll 1
    for (int i = t; i < 16384; i += 512) {
        int j = i >> 10, r = i & 1023, row = r >> 5, col = r & 31;
        float val = 0.0f;
        if (j < 8) {            // Q_m stored [v=row][u=col]
            int m = j, v = row, u = col;
            if (u < 25 && v < 25)
                val = fast_tanh(x1s[m * 25 + u] * x2s[m * 25 + v] * 0.2f);
        } else {                // P_m stored [u=row][v=col]
            int m = j - 8, u = row, v = col;
            if (u < 25 && v < 25) {
                float dw0 = diff_w[2 * m], dw1 = diff_w[2 * m + 1];
                float a;
                if (m < 4) {
                    int j0 = 2 * m, j1 = j0 + 1;
                    a = dw0 * (x1s[j0 * 25 + u] - x2s[j0 * 25 + v])
                      + dw1 * (x1s[j1 * 25 + u] - x2s[j1 * 25 + v]);
                } else {
                    int j0 = 2 * m - 8, j1 = j0 + 1;
                    a = dw0 * (x2s[j0 * 25 + u] - x1s[j0 * 25 + v])
                      + dw1 * (x2s[j1 * 25 + u] - x1s[j1 * 25 + v]);
                }
                val = fast_tanh(a + diff_b[m]);
            }
        }
        Bmats[i] = (__bf16)val;
    }
    if (t < 64) {
        float s = 0.0f;
        #pragma unroll 1
        for (int v = 0; v < 25; ++v) s += x3s[t * 25 + v];
        S3s[t] = s;
    }
    __syncthreads();

    // ===== A/B MFMA: waves 0-3 -> xatt (j 0..7), waves 4-7 -> gcnp (j 8..16) =====
    {
        const int ln = c & 15, kq = c >> 4;
        const int grp = w >> 2;
        const int mt  = w & 3;
        const int arow = mt * 16 + ln;

        const bf16x8 araw = *(const bf16x8*)&x3bf[arow * 32 + kq * 8];
        float av[8];
        #pragma unroll
        for (int e = 0; e < 8; ++e) av[e] = (float)araw[e];

        f32x4 acc0 = {0.f, 0.f, 0.f, 0.f};
        f32x4 acc1 = {0.f, 0.f, 0.f, 0.f};
        const float* scT = grp ? edge_wT : att_wT;
        const int jbase = grp ? 8 : 0;

        #pragma unroll 1
        for (int j = 0; j < 8; ++j) {
            float sj = scT[j * 64 + arow];
            bf16x8 aj;
            #pragma unroll
            for (int e = 0; e < 8; ++e) aj[e] = (__bf16)(av[e] * sj);
            const __bf16* bb = &Bmats[(jbase + j) * 1024 + kq * 8];
            bf16x8 b0 = *(const bf16x8*)(bb + ln * 32);
            bf16x8 b1 = *(const bf16x8*)(bb + (16 + ln) * 32);
            acc0 = __builtin_amdgcn_mfma_f32_16x16x32_bf16(aj, b0, acc0, 0, 0, 0);
            acc1 = __builtin_amdgcn_mfma_f32_16x16x32_bf16(aj, b1, acc1, 0, 0, 0);
        }
        if (grp) {  // + A_static @ x3 (unit scale)
            const __bf16* bb = &Bmats[16 * 1024 + kq * 8];
            bf16x8 b0 = *(const bf16x8*)(bb + ln * 32);
            bf16x8 b1 = *(const bf16x8*)(bb + (16 + ln) * 32);
            acc0 = __builtin_amdgcn_mfma_f32_16x16x32_bf16(araw, b0, acc0, 0, 0, 0);
            acc1 = __builtin_amdgcn_mfma_f32_16x16x32_bf16(araw, b1, acc1, 0, 0, 0);
        }
        float* dstArr = grp ? gcnp : xatt;
        #pragma unroll
        for (int r = 0; r < 4; ++r) {
            int row = mt * 16 + kq * 4 + r;
            float bias = grp ? (alpha * edge_b[row] * S3s[row])
                             : (att_b[row] * S3s[row]);
            dstArr[row * 25 + ln] = acc0[r] + bias;
            if (ln < 9) dstArr[row * 25 + 16 + ln] = acc1[r] + bias;
        }
    }
    __syncthreads();

    // ===== MLP on wave 0 (t==c), shfl-based =====
    if (t < 64) {
        float xm = 0.0f;
        #pragma unroll 1
        for (int v = 0; v < 25; ++v) xm += xatt[c * 25 + v];
        xm *= 0.04f;
        float a1 = 0.0f;
        #pragma unroll 1
        for (int i4 = 0; i4 < 16; ++i4) {
            float4 wv; wv.x = wv.y = wv.z = wv.w = 0.0f;
            if (c < 32) wv = *(const float4*)&cc1_w[c * 64 + 4 * i4];
            a1 += wv.x * __shfl(xm, 4 * i4 + 0, 64);
            a1 += wv.y * __shfl(xm, 4 * i4 + 1, 64);
            a1 += wv.z * __shfl(xm, 4 * i4 + 2, 64);
            a1 += wv.w * __shfl(xm, 4 * i4 + 3, 64);
        }
        float h = 0.0f;
        if (c < 32) {
            a1 += cc1_b[c];
            a1 = (a1 - bn_m[c]) * (bn_g[c] * rsqrtf(bn_v[c] + 1e-5f)) + bn_b[c];
            h = 0.5f * a1 * (1.0f + erff(a1 * 0.70710678118654752f));
        }
        float a2 = cc2_b[c];
        #pragma unroll 1
        for (int i4 = 0; i4 < 8; ++i4) {
            float4 wv = *(const float4*)&cc2_w[c * 32 + 4 * i4];
            a2 += wv.x * __shfl(h, 4 * i4 + 0, 64);
            a2 += wv.y * __shfl(h, 4 * i4 + 1, 64);
            a2 += wv.z * __shfl(h, 4 * i4 + 2, 64);
            a2 += wv.w * __shfl(h, 4 * i4 + 3, 64);
        }
        catt[c] = fast_sigmoid(a2);
    }
    __syncthreads();

    // ===== spatial attention: 8 lanes per v =====
    if (t < 200) {
        int v = t >> 3, s8 = t & 7;
        float p = 0.0f;
        #pragma unroll
        for (int k = 0; k < 8; ++k) {
            int cc = s8 + 8 * k;
            p += cs_w[cc] * gcnp[cc * 25 + v] * catt[cc];
        }
        p += __shfl_down(p, 4, 8);
        p += __shfl_down(p, 2, 8);
        p += __shfl_down(p, 1, 8);
        if (s8 == 0) satt[v] = fast_sigmoid(p + cs_b[0]);
    }
    __syncthreads();

    // ===== out = gcn*catt + xatt*satt + x (x re-read from global, L2-hit) =====
    float* ob = out + (size_t)b * 1600;
    #pragma unroll 1
    for (int i = t; i < 1600; i += 512) {
        int cc = i / 25, v = i - cc * 25;
        ob[i] = gcnp[i] * catt[cc] + xatt[i] * satt[v] + xb[i];
    }
}

extern "C" void kernel_launch(void* const* d_in, const int* in_sizes, int n_in,
                              void* d_out, int out_size, void* d_ws, size_t ws_size,
                              hipStream_t stream) {
    const float* x        = (const float*)d_in[0];
    const float* A_static = (const float*)d_in[1];
    const float* w1       = (const float*)d_in[2];
    const float* b1       = (const float*)d_in[3];
    const float* w2       = (const float*)d_in[4];
    const float* b2       = (const float*)d_in[5];
    const float* w3       = (const float*)d_in[6];
    const float* b3       = (const float*)d_in[7];
    const float* diff_w   = (const float*)d_in[8];
    const float* diff_b   = (const float*)d_in[9];
    const float* edge_w   = (const float*)d_in[10];
    const float* edge_b   = (const float*)d_in[11];
    const float* att_w    = (const float*)d_in[12];
    const float* att_b    = (const float*)d_in[13];
    const float* cc1_w    = (const float*)d_in[14];
    const float* cc1_b    = (const float*)d_in[15];
    const float* bn_g     = (const float*)d_in[16];
    const float* bn_b     = (const float*)d_in[17];
    const float* bn_m     = (const float*)d_in[18];
    const float* bn_v     = (const float*)d_in[19];
    const float* cc2_w    = (const float*)d_in[20];
    const float* cc2_b    = (const float*)d_in[21];
    const float* cs_w     = (const float*)d_in[22];
    const float* cs_b     = (const float*)d_in[23];
    const float* alpha    = (const float*)d_in[24];
    float* outp = (float*)d_out;

    cga_fused<<<NB, 512, 0, stream>>>(x, A_static, w1, b1, w2, b2, w3, b3,
                                      diff_w, diff_b, edge_w, edge_b,
                                      att_w, att_b, cc1_w, cc1_b,
                                      bn_g, bn_b, bn_m, bn_v,
                                      cc2_w, cc2_b, cs_w, cs_b, alpha, outp);
}

// Round 10
// 25.143 us; speedup vs baseline: 2.7146x; 1.0202x over previous
//
#include <hip/hip_runtime.h>
#include <math.h>

#define NB   512

typedef __attribute__((ext_vector_type(8))) __bf16 bf16x8;
typedef __attribute__((ext_vector_type(4))) float  f32x4;

__device__ __forceinline__ float fast_rcp(float x) { return __builtin_amdgcn_rcpf(x); }
__device__ __forceinline__ float fast_tanh(float x) {
    float e = __expf(2.0f * x);
    return 1.0f - 2.0f * fast_rcp(e + 1.0f);
}
__device__ __forceinline__ float fast_sigmoid(float x) {
    return fast_rcp(1.0f + __expf(-x));
}
__device__ __forceinline__ unsigned pack_bf16(float a, float b) {
    unsigned short ux = __builtin_bit_cast(unsigned short, (__bf16)a);
    unsigned short uy = __builtin_bit_cast(unsigned short, (__bf16)b);
    return (unsigned)ux | ((unsigned)uy << 16);
}
__device__ __forceinline__ float bf16_res(float v) {   // v - bf16(v)
    return v - (float)(__bf16)v;
}

__global__ __launch_bounds__(512, 4)
void cga_fused(const float* __restrict__ x,
               const float* __restrict__ A_static,
               const float* __restrict__ w1, const float* __restrict__ b1,
               const float* __restrict__ w2, const float* __restrict__ b2,
               const float* __restrict__ w3, const float* __restrict__ b3,
               const float* __restrict__ diff_w, const float* __restrict__ diff_b,
               const float* __restrict__ edge_w, const float* __restrict__ edge_b,
               const float* __restrict__ att_w, const float* __restrict__ att_b,
               const float* __restrict__ cc1_w, const float* __restrict__ cc1_b,
               const float* __restrict__ bn_g, const float* __restrict__ bn_b,
               const float* __restrict__ bn_m, const float* __restrict__ bn_v,
               const float* __restrict__ cc2_w, const float* __restrict__ cc2_b,
               const float* __restrict__ cs_w, const float* __restrict__ cs_b,
               const float* __restrict__ alpha_p,
               float* __restrict__ out)
{
    const int b = blockIdx.x;
    const int t = threadIdx.x;
    const int c = t & 63;   // lane
    const int w = t >> 6;   // wave 0..7

    // Bmats: j=0..7 Q_m as B[n=v][k=u]; j=8..15 P_m as B[n=u][k=v]; j=16 A_static [n=u][k=v].
    // Before P2, Bmats elems [0..5119] alias wA hi [80][64], [5120..10239] wA lo.
    __shared__ __align__(16) __bf16 Bmats[17 * 32 * 32];   // 34816 B
    __shared__ __align__(16) __bf16 x3bf[64 * 32];         // A-operand of A/B phase [c][k=v]
    __shared__ __align__(16) __bf16 xT[2 * 32 * 72];       // x^T hi/lo planes [v][cin], stride 72
    __shared__ float x1s[200], x2s[200];
    __shared__ float xatt[1600], gcnp[1600];
    __shared__ float att_wT[512], edge_wT[512];            // [j][c], edge pre-scaled by alpha
    __shared__ float S3s[64], catt[64], satt[32];

    const float alpha = alpha_p[0];
    const float* xb = x + (size_t)b * 1600;
    __bf16* const xThi = xT;
    __bf16* const xTlo = xT + 32 * 72;

    // ===== stage: x (coalesced read -> transposed hi/lo), wA (hi+lo), misc =====
    {
        #pragma unroll 1
        for (int i = t; i < 1600; i += 512) {           // coalesced fp32 read
            int cin = i / 25, v = i - cin * 25;
            float f = xb[i];
            __bf16 h = (__bf16)f;
            xThi[v * 72 + cin] = h;
            xTlo[v * 72 + cin] = (__bf16)(f - (float)h);
        }
        #pragma unroll 1
        for (int i = t; i < 1008; i += 512) {           // zero pad rows v=25..31, both planes
            int p = (i >= 504), r = i - p * 504;
            (p ? xTlo : xThi)[25 * 72 + r] = (__bf16)0.f;
        }
        unsigned* wA32   = (unsigned*)Bmats;
        unsigned* wAlo32 = wA32 + 2560;
        #pragma unroll 1
        for (int i = t; i < 2048; i += 512) {
            float2 wv = *(const float2*)&w3[2 * i];
            wA32[i]   = pack_bf16(wv.x, wv.y);
            wAlo32[i] = pack_bf16(bf16_res(wv.x), bf16_res(wv.y));
        }
        {   // w1 -> rows 64-71, w2 -> rows 72-79 (256 u32 each)
            int which = t >> 8, j = t & 255;
            const float* wsrc = which ? w2 : w1;
            float2 wv = *(const float2*)&wsrc[2 * j];
            wA32[2048 + t]   = pack_bf16(wv.x, wv.y);
            wAlo32[2048 + t] = pack_bf16(bf16_res(wv.x), bf16_res(wv.y));
        }
        unsigned* x3b32 = (unsigned*)x3bf;
        #pragma unroll 1
        for (int i = t; i < 1024; i += 512) x3b32[i] = 0u;
        {   // att_wT[j][c], edge_wT[j][c] (alpha folded)
            int j = t >> 6;
            att_wT [j * 64 + c] = att_w [c * 8 + j];
            edge_wT[j * 64 + c] = alpha * edge_w[c * 8 + j];
        }
        {   // A_static -> Bmats[16][n=u][k=v], zero-padded
            int n = t >> 4, p = t & 15;
            int k0 = 2 * p, k1 = k0 + 1;
            float a0 = (n < 25 && k0 < 25) ? A_static[n * 25 + k0] : 0.0f;
            float a1 = (n < 25 && k1 < 25) ? A_static[n * 25 + k1] : 0.0f;
            ((unsigned*)Bmats)[16 * 512 + n * 16 + p] = pack_bf16(a0, a1);
        }
    }
    __syncthreads();

    // ===== P1 (split-bf16 MFMA): [x3; x1; x2] = wA(80x64) @ x(64x25) =====
    // acc = wHi*xHi + wHi*xLo + wLo*xHi
    {
        const int ln = c & 15, kq = c >> 4;
        #pragma unroll 1
        for (int pass = 0; pass < 2; ++pass) {
            const int jb = pass ? (w + 8) : w;
            if (jb <= 9) {
                const int nt = (jb >= 5) ? 1 : 0;
                const int mt = jb - nt * 5;
                const int arow = mt * 16 + ln;
                const int brow = nt * 16 + ln;
                f32x4 acc = {0.f, 0.f, 0.f, 0.f};
                bf16x8 ah0 = *(const bf16x8*)&Bmats[arow * 64 + kq * 8];
                bf16x8 ah1 = *(const bf16x8*)&Bmats[arow * 64 + 32 + kq * 8];
                bf16x8 al0 = *(const bf16x8*)&Bmats[5120 + arow * 64 + kq * 8];
                bf16x8 al1 = *(const bf16x8*)&Bmats[5120 + arow * 64 + 32 + kq * 8];
                bf16x8 bh0 = *(const bf16x8*)&xThi[brow * 72 + kq * 8];
                bf16x8 bh1 = *(const bf16x8*)&xThi[brow * 72 + 32 + kq * 8];
                bf16x8 bl0 = *(const bf16x8*)&xTlo[brow * 72 + kq * 8];
                bf16x8 bl1 = *(const bf16x8*)&xTlo[brow * 72 + 32 + kq * 8];
                acc = __builtin_amdgcn_mfma_f32_16x16x32_bf16(ah0, bh0, acc, 0, 0, 0);
                acc = __builtin_amdgcn_mfma_f32_16x16x32_bf16(ah1, bh1, acc, 0, 0, 0);
                acc = __builtin_amdgcn_mfma_f32_16x16x32_bf16(ah0, bl0, acc, 0, 0, 0);
                acc = __builtin_amdgcn_mfma_f32_16x16x32_bf16(ah1, bl1, acc, 0, 0, 0);
                acc = __builtin_amdgcn_mfma_f32_16x16x32_bf16(al0, bh0, acc, 0, 0, 0);
                acc = __builtin_amdgcn_mfma_f32_16x16x32_bf16(al1, bh1, acc, 0, 0, 0);
                const int colv = nt * 16 + ln;
                if (colv < 25) {
                    if (mt < 4) {
                        #pragma unroll
                        for (int r = 0; r < 4; ++r) {
                            int cc = mt * 16 + kq * 4 + r;
                            float val = acc[r] + b3[cc];
                            x3bf[cc * 32 + colv] = (__bf16)val;
                        }
                    } else {
                        #pragma unroll
                        for (int r = 0; r < 4; ++r) {
                            int row16 = kq * 4 + r;
                            int which = row16 >> 3, m = row16 & 7;
                            float val = acc[r] + (which ? b2[m] : b1[m]);
                            (which ? x2s : x1s)[m * 25 + colv] = val;
                        }
                    }
                }
            }
        }
    }
    __syncthreads();

    // ===== P2: generate Q (j<8) / P (j>=8) incl. zero pads; S3 on t<64 =====
    #pragma unroll 1
    for (int i = t; i < 16384; i += 512) {
        int j = i >> 10, r = i & 1023, row = r >> 5, col = r & 31;
        float val = 0.0f;
        if (j < 8) {            // Q_m stored [v=row][u=col]
            int m = j, v = row, u = col;
            if (u < 25 && v < 25)
                val = fast_tanh(x1s[m * 25 + u] * x2s[m * 25 + v] * 0.2f);
        } else {                // P_m stored [u=row][v=col]
            int m = j - 8, u = row, v = col;
            if (u < 25 && v < 25) {
                float dw0 = diff_w[2 * m], dw1 = diff_w[2 * m + 1];
                float a;
                if (m < 4) {
                    int j0 = 2 * m, j1 = j0 + 1;
                    a = dw0 * (x1s[j0 * 25 + u] - x2s[j0 * 25 + v])
                      + dw1 * (x1s[j1 * 25 + u] - x2s[j1 * 25 + v]);
                } else {
                    int j0 = 2 * m - 8, j1 = j0 + 1;
                    a = dw0 * (x2s[j0 * 25 + u] - x1s[j0 * 25 + v])
                      + dw1 * (x2s[j1 * 25 + u] - x1s[j1 * 25 + v]);
                }
                val = fast_tanh(a + diff_b[m]);
            }
        }
        Bmats[i] = (__bf16)val;
    }
    if (t < 64) {               // S3 from zero-padded bf16 x3 row (vector reads)
        const bf16x8* xr = (const bf16x8*)&x3bf[t * 32];
        float s = 0.0f;
        #pragma unroll
        for (int q = 0; q < 4; ++q) {
            bf16x8 vq = xr[q];
            #pragma unroll
            for (int e = 0; e < 8; ++e) s += (float)vq[e];
        }
        S3s[t] = s;
    }
    __syncthreads();

    // ===== A/B MFMA: waves 0-3 -> xatt (j 0..7), waves 4-7 -> gcnp (j 8..16) =====
    {
        const int ln = c & 15, kq = c >> 4;
        const int grp = w >> 2;
        const int mt  = w & 3;
        const int arow = mt * 16 + ln;

        const bf16x8 araw = *(const bf16x8*)&x3bf[arow * 32 + kq * 8];
        float av[8];
        #pragma unroll
        for (int e = 0; e < 8; ++e) av[e] = (float)araw[e];

        f32x4 acc0 = {0.f, 0.f, 0.f, 0.f};
        f32x4 acc1 = {0.f, 0.f, 0.f, 0.f};
        const float* scT = grp ? edge_wT : att_wT;
        const int jbase = grp ? 8 : 0;

        #pragma unroll 1
        for (int j = 0; j < 8; ++j) {
            float sj = scT[j * 64 + arow];
            bf16x8 aj;
            #pragma unroll
            for (int e = 0; e < 8; ++e) aj[e] = (__bf16)(av[e] * sj);
            const __bf16* bb = &Bmats[(jbase + j) * 1024 + kq * 8];
            bf16x8 b0 = *(const bf16x8*)(bb + ln * 32);
            bf16x8 b1 = *(const bf16x8*)(bb + (16 + ln) * 32);
            acc0 = __builtin_amdgcn_mfma_f32_16x16x32_bf16(aj, b0, acc0, 0, 0, 0);
            acc1 = __builtin_amdgcn_mfma_f32_16x16x32_bf16(aj, b1, acc1, 0, 0, 0);
        }
        if (grp) {  // + A_static @ x3 (unit scale)
            const __bf16* bb = &Bmats[16 * 1024 + kq * 8];
            bf16x8 b0 = *(const bf16x8*)(bb + ln * 32);
            bf16x8 b1 = *(const bf16x8*)(bb + (16 + ln) * 32);
            acc0 = __builtin_amdgcn_mfma_f32_16x16x32_bf16(araw, b0, acc0, 0, 0, 0);
            acc1 = __builtin_amdgcn_mfma_f32_16x16x32_bf16(araw, b1, acc1, 0, 0, 0);
        }
        float* dstArr = grp ? gcnp : xatt;
        #pragma unroll
        for (int r = 0; r < 4; ++r) {
            int row = mt * 16 + kq * 4 + r;
            float bias = grp ? (alpha * edge_b[row] * S3s[row])
                             : (att_b[row] * S3s[row]);
            dstArr[row * 25 + ln] = acc0[r] + bias;
            if (ln < 9) dstArr[row * 25 + 16 + ln] = acc1[r] + bias;
        }
    }
    __syncthreads();

    // ===== MLP on wave 0 (t==c), shfl-based =====
    if (t < 64) {
        float xm = 0.0f;
        #pragma unroll 1
        for (int v = 0; v < 25; ++v) xm += xatt[c * 25 + v];
        xm *= 0.04f;
        float a1 = 0.0f;
        #pragma unroll 1
        for (int i4 = 0; i4 < 16; ++i4) {
            float4 wv; wv.x = wv.y = wv.z = wv.w = 0.0f;
            if (c < 32) wv = *(const float4*)&cc1_w[c * 64 + 4 * i4];
            a1 += wv.x * __shfl(xm, 4 * i4 + 0, 64);
            a1 += wv.y * __shfl(xm, 4 * i4 + 1, 64);
            a1 += wv.z * __shfl(xm, 4 * i4 + 2, 64);
            a1 += wv.w * __shfl(xm, 4 * i4 + 3, 64);
        }
        float h = 0.0f;
        if (c < 32) {
            a1 += cc1_b[c];
            a1 = (a1 - bn_m[c]) * (bn_g[c] * rsqrtf(bn_v[c] + 1e-5f)) + bn_b[c];
            h = 0.5f * a1 * (1.0f + erff(a1 * 0.70710678118654752f));
        }
        float a2 = cc2_b[c];
        #pragma unroll 1
        for (int i4 = 0; i4 < 8; ++i4) {
            float4 wv = *(const float4*)&cc2_w[c * 32 + 4 * i4];
            a2 += wv.x * __shfl(h, 4 * i4 + 0, 64);
            a2 += wv.y * __shfl(h, 4 * i4 + 1, 64);
            a2 += wv.z * __shfl(h, 4 * i4 + 2, 64);
            a2 += wv.w * __shfl(h, 4 * i4 + 3, 64);
        }
        catt[c] = fast_sigmoid(a2);
    }
    __syncthreads();

    // ===== spatial attention: 8 lanes per v =====
    if (t < 200) {
        int v = t >> 3, s8 = t & 7;
        float p = 0.0f;
        #pragma unroll
        for (int k = 0; k < 8; ++k) {
            int cc = s8 + 8 * k;
            p += cs_w[cc] * gcnp[cc * 25 + v] * catt[cc];
        }
        p += __shfl_down(p, 4, 8);
        p += __shfl_down(p, 2, 8);
        p += __shfl_down(p, 1, 8);
        if (s8 == 0) satt[v] = fast_sigmoid(p + cs_b[0]);
    }
    __syncthreads();

    // ===== out = gcn*catt + xatt*satt + x (x re-read from global, L2-hit) =====
    float* ob = out + (size_t)b * 1600;
    #pragma unroll 1
    for (int i = t; i < 1600; i += 512) {
        int cc = i / 25, v = i - cc * 25;
        ob[i] = gcnp[i] * catt[cc] + xatt[i] * satt[v] + xb[i];
    }
}

extern "C" void kernel_launch(void* const* d_in, const int* in_sizes, int n_in,
                              void* d_out, int out_size, void* d_ws, size_t ws_size,
                              hipStream_t stream) {
    const float* x        = (const float*)d_in[0];
    const float* A_static = (const float*)d_in[1];
    const float* w1       = (const float*)d_in[2];
    const float* b1       = (const float*)d_in[3];
    const float* w2       = (const float*)d_in[4];
    const float* b2       = (const float*)d_in[5];
    const float* w3       = (const float*)d_in[6];
    const float* b3       = (const float*)d_in[7];
    const float* diff_w   = (const float*)d_in[8];
    const float* diff_b   = (const float*)d_in[9];
    const float* edge_w   = (const float*)d_in[10];
    const float* edge_b   = (const float*)d_in[11];
    const float* att_w    = (const float*)d_in[12];
    const float* att_b    = (const float*)d_in[13];
    const float* cc1_w    = (const float*)d_in[14];
    const float* cc1_b    = (const float*)d_in[15];
    const float* bn_g     = (const float*)d_in[16];
    const float* bn_b     = (const float*)d_in[17];
    const float* bn_m     = (const float*)d_in[18];
    const float* bn_v     = (const float*)d_in[19];
    const float* cc2_w    = (const float*)d_in[20];
    const float* cc2_b    = (const float*)d_in[21];
    const float* cs_w     = (const float*)d_in[22];
    const float* cs_b     = (const float*)d_in[23];
    const float* alpha    = (const float*)d_in[24];
    float* outp = (float*)d_out;

    cga_fused<<<NB, 512, 0, stream>>>(x, A_static, w1, b1, w2, b2, w3, b3,
                                      diff_w, diff_b, edge_w, edge_b,
                                      att_w, att_b, cc1_w, cc1_b,
                                      bn_g, bn_b, bn_m, bn_v,
                                      cc2_w, cc2_b, cs_w, cs_b, alpha, outp);
}

// Round 11
// 21.718 us; speedup vs baseline: 3.1427x; 1.1577x over previous
//
#include <hip/hip_runtime.h>
#include <math.h>

#define NB   512

typedef __attribute__((ext_vector_type(8))) __bf16 bf16x8;
typedef __attribute__((ext_vector_type(4))) float  f32x4;

__device__ __forceinline__ float fast_rcp(float x) { return __builtin_amdgcn_rcpf(x); }
__device__ __forceinline__ float fast_tanh(float x) {
    float e = __expf(2.0f * x);
    return 1.0f - 2.0f * fast_rcp(e + 1.0f);
}
__device__ __forceinline__ float fast_sigmoid(float x) {
    return fast_rcp(1.0f + __expf(-x));
}
__device__ __forceinline__ unsigned pack_bf16(float a, float b) {
    unsigned short ux = __builtin_bit_cast(unsigned short, (__bf16)a);
    unsigned short uy = __builtin_bit_cast(unsigned short, (__bf16)b);
    return (unsigned)ux | ((unsigned)uy << 16);
}
__device__ __forceinline__ float bf16_res(float v) {   // v - bf16(v)
    return v - (float)(__bf16)v;
}

__global__ __launch_bounds__(512, 4)
void cga_fused(const float* __restrict__ x,
               const float* __restrict__ A_static,
               const float* __restrict__ w1, const float* __restrict__ b1,
               const float* __restrict__ w2, const float* __restrict__ b2,
               const float* __restrict__ w3, const float* __restrict__ b3,
               const float* __restrict__ diff_w, const float* __restrict__ diff_b,
               const float* __restrict__ edge_w, const float* __restrict__ edge_b,
               const float* __restrict__ att_w, const float* __restrict__ att_b,
               const float* __restrict__ cc1_w, const float* __restrict__ cc1_b,
               const float* __restrict__ bn_g, const float* __restrict__ bn_b,
               const float* __restrict__ bn_m, const float* __restrict__ bn_v,
               const float* __restrict__ cc2_w, const float* __restrict__ cc2_b,
               const float* __restrict__ cs_w, const float* __restrict__ cs_b,
               const float* __restrict__ alpha_p,
               float* __restrict__ out)
{
    const int b = blockIdx.x;
    const int t = threadIdx.x;
    const int c = t & 63;   // lane
    const int w = t >> 6;   // wave 0..7

    // Bmats: j=0..7 Q_m as B[n=v][k=u]; j=8..15 P_m as B[n=u][k=v]; j=16 A_static [n=u][k=v].
    // Before P2, Bmats elems [0..5119] alias wA hi [80][64] (XOR-swizzled fragments),
    // [5120..10239] wA lo. A_static block (elems 16384..) untouched by staging.
    __shared__ __align__(16) __bf16 Bmats[17 * 32 * 32];   // 34816 B
    __shared__ __align__(16) __bf16 x3bf[64 * 32];         // A-operand of A/B phase [c][k=v]
    __shared__ __align__(16) __bf16 xT[2 * 32 * 72];       // x^T hi/lo planes [v][cin], stride 72
    __shared__ float x1s[200], x2s[200];
    __shared__ float xatt[1600], gcnp[1600];
    __shared__ float att_wT[512], edge_wT[512];            // [j][c], edge pre-scaled by alpha
    __shared__ float S3s[64], catt[64], satt[32];
    __shared__ float xmean[64], hbuf[32], csct[64];

    const float alpha = alpha_p[0];
    const float* xb = x + (size_t)b * 1600;
    __bf16* const xThi = xT;
    __bf16* const xTlo = xT + 32 * 72;

    // ===== x preload into registers (reused by staging AND epilogue) =====
    float xv[4];
    xv[0] = xb[t]; xv[1] = xb[t + 512]; xv[2] = xb[t + 1024];
    xv[3] = (t < 64) ? xb[t + 1536] : 0.0f;

    // ===== stage: x -> transposed hi/lo, wA hi/lo (swizzled), misc =====
    {
        #pragma unroll
        for (int k = 0; k < 4; ++k) {
            int i = t + 512 * k;
            if (i < 1600) {
                int cin = i / 25, v = i - cin * 25;
                float f = xv[k];
                __bf16 h = (__bf16)f;
                xThi[v * 72 + cin] = h;
                xTlo[v * 72 + cin] = (__bf16)(f - (float)h);
            }
        }
        #pragma unroll 1
        for (int i = t; i < 1008; i += 512) {           // zero pad rows v=25..31, both planes
            int p = (i >= 504), r = i - p * 504;
            (p ? xTlo : xThi)[25 * 72 + r] = (__bf16)0.f;
        }
        // wA fragments, XOR-swizzled: dword sw = i ^ (((i>>5)&7)<<2)
        unsigned* wA32   = (unsigned*)Bmats;
        unsigned* wAlo32 = wA32 + 2560;
        #pragma unroll 1
        for (int i = t; i < 2048; i += 512) {
            float2 wv = *(const float2*)&w3[2 * i];
            int sw = i ^ (((i >> 5) & 7) << 2);
            wA32[sw]   = pack_bf16(wv.x, wv.y);
            wAlo32[sw] = pack_bf16(bf16_res(wv.x), bf16_res(wv.y));
        }
        {   // w1 -> rows 64-71, w2 -> rows 72-79 (256 u32 each)
            int which = t >> 8, j = t & 255;
            const float* wsrc = which ? w2 : w1;
            float2 wv = *(const float2*)&wsrc[2 * j];
            int i2 = 2048 + t;
            int sw = i2 ^ (((i2 >> 5) & 7) << 2);
            wA32[sw]   = pack_bf16(wv.x, wv.y);
            wAlo32[sw] = pack_bf16(bf16_res(wv.x), bf16_res(wv.y));
        }
        unsigned* x3b32 = (unsigned*)x3bf;
        #pragma unroll 1
        for (int i = t; i < 1024; i += 512) x3b32[i] = 0u;
        {   // att_wT[j][c], edge_wT[j][c] (alpha folded)
            int j = t >> 6;
            att_wT [j * 64 + c] = att_w [c * 8 + j];
            edge_wT[j * 64 + c] = alpha * edge_w[c * 8 + j];
        }
        {   // A_static -> Bmats[16][n=u][k=v], zero-padded
            int n = t >> 4, p = t & 15;
            int k0 = 2 * p, k1 = k0 + 1;
            float a0 = (n < 25 && k0 < 25) ? A_static[n * 25 + k0] : 0.0f;
            float a1 = (n < 25 && k1 < 25) ? A_static[n * 25 + k1] : 0.0f;
            ((unsigned*)Bmats)[16 * 512 + n * 16 + p] = pack_bf16(a0, a1);
        }
    }
    __syncthreads();

    // ===== P1 (split-bf16 MFMA): [x3; x1; x2] = wA(80x64) @ x(64x25) =====
    {
        const int ln = c & 15, kq = c >> 4;
        #pragma unroll 1
        for (int pass = 0; pass < 2; ++pass) {
            const int jb = pass ? (w + 8) : w;
            if (jb <= 9) {
                const int nt = (jb >= 5) ? 1 : 0;
                const int mt = jb - nt * 5;
                const int arow = mt * 16 + ln;
                const int brow = nt * 16 + ln;
                const int r7 = arow & 7;
                const __bf16* hiB = Bmats        + arow * 64;
                const __bf16* loB = Bmats + 5120 + arow * 64;
                f32x4 acc = {0.f, 0.f, 0.f, 0.f};
                bf16x8 ah0 = *(const bf16x8*)(hiB + (((kq    ) ^ r7) << 3));
                bf16x8 ah1 = *(const bf16x8*)(hiB + (((kq + 4) ^ r7) << 3));
                bf16x8 al0 = *(const bf16x8*)(loB + (((kq    ) ^ r7) << 3));
                bf16x8 al1 = *(const bf16x8*)(loB + (((kq + 4) ^ r7) << 3));
                bf16x8 bh0 = *(const bf16x8*)&xThi[brow * 72 + kq * 8];
                bf16x8 bh1 = *(const bf16x8*)&xThi[brow * 72 + 32 + kq * 8];
                bf16x8 bl0 = *(const bf16x8*)&xTlo[brow * 72 + kq * 8];
                bf16x8 bl1 = *(const bf16x8*)&xTlo[brow * 72 + 32 + kq * 8];
                acc = __builtin_amdgcn_mfma_f32_16x16x32_bf16(ah0, bh0, acc, 0, 0, 0);
                acc = __builtin_amdgcn_mfma_f32_16x16x32_bf16(ah1, bh1, acc, 0, 0, 0);
                acc = __builtin_amdgcn_mfma_f32_16x16x32_bf16(ah0, bl0, acc, 0, 0, 0);
                acc = __builtin_amdgcn_mfma_f32_16x16x32_bf16(ah1, bl1, acc, 0, 0, 0);
                acc = __builtin_amdgcn_mfma_f32_16x16x32_bf16(al0, bh0, acc, 0, 0, 0);
                acc = __builtin_amdgcn_mfma_f32_16x16x32_bf16(al1, bh1, acc, 0, 0, 0);
                const int colv = nt * 16 + ln;
                if (colv < 25) {
                    if (mt < 4) {
                        #pragma unroll
                        for (int r = 0; r < 4; ++r) {
                            int cc = mt * 16 + kq * 4 + r;
                            float val = acc[r] + b3[cc];
                            x3bf[cc * 32 + colv] = (__bf16)val;
                        }
                    } else {
                        #pragma unroll
                        for (int r = 0; r < 4; ++r) {
                            int row16 = kq * 4 + r;
                            int which = row16 >> 3, m = row16 & 7;
                            float val = acc[r] + (which ? b2[m] : b1[m]);
                            (which ? x2s : x1s)[m * 25 + colv] = val;
                        }
                    }
                }
            }
        }
    }
    __syncthreads();

    // ===== P2: generate Q (j<8) / P (j>=8) incl. zero pads; S3 on t<64 =====
    #pragma unroll 1
    for (int i = t; i < 16384; i += 512) {
        int j = i >> 10, r = i & 1023, row = r >> 5, col = r & 31;
        float val = 0.0f;
        if (j < 8) {            // Q_m stored [v=row][u=col]
            int m = j, v = row, u = col;
            if (u < 25 && v < 25)
                val = fast_tanh(x1s[m * 25 + u] * x2s[m * 25 + v] * 0.2f);
        } else {                // P_m stored [u=row][v=col]
            int m = j - 8, u = row, v = col;
            if (u < 25 && v < 25) {
                float dw0 = diff_w[2 * m], dw1 = diff_w[2 * m + 1];
                float a;
                if (m < 4) {
                    int j0 = 2 * m, j1 = j0 + 1;
                    a = dw0 * (x1s[j0 * 25 + u] - x2s[j0 * 25 + v])
                      + dw1 * (x1s[j1 * 25 + u] - x2s[j1 * 25 + v]);
                } else {
                    int j0 = 2 * m - 8, j1 = j0 + 1;
                    a = dw0 * (x2s[j0 * 25 + u] - x1s[j0 * 25 + v])
                      + dw1 * (x2s[j1 * 25 + u] - x1s[j1 * 25 + v]);
                }
                val = fast_tanh(a + diff_b[m]);
            }
        }
        Bmats[i] = (__bf16)val;
    }
    if (t < 64) {               // S3 from zero-padded bf16 x3 row (vector reads)
        const bf16x8* xr = (const bf16x8*)&x3bf[t * 32];
        float s = 0.0f;
        #pragma unroll
        for (int q = 0; q < 4; ++q) {
            bf16x8 vq = xr[q];
            #pragma unroll
            for (int e = 0; e < 8; ++e) s += (float)vq[e];
        }
        S3s[t] = s;
    }
    __syncthreads();

    // ===== A/B MFMA: waves 0-3 -> xatt (j 0..7), waves 4-7 -> gcnp (j 8..16) =====
    {
        const int ln = c & 15, kq = c >> 4;
        const int grp = w >> 2;
        const int mt  = w & 3;
        const int arow = mt * 16 + ln;

        const bf16x8 araw = *(const bf16x8*)&x3bf[arow * 32 + kq * 8];
        float av[8];
        #pragma unroll
        for (int e = 0; e < 8; ++e) av[e] = (float)araw[e];

        f32x4 acc0 = {0.f, 0.f, 0.f, 0.f};
        f32x4 acc1 = {0.f, 0.f, 0.f, 0.f};
        const float* scT = grp ? edge_wT : att_wT;
        const int jbase = grp ? 8 : 0;

        #pragma unroll 1
        for (int j = 0; j < 8; ++j) {
            float sj = scT[j * 64 + arow];
            bf16x8 aj;
            #pragma unroll
            for (int e = 0; e < 8; ++e) aj[e] = (__bf16)(av[e] * sj);
            const __bf16* bb = &Bmats[(jbase + j) * 1024 + kq * 8];
            bf16x8 b0 = *(const bf16x8*)(bb + ln * 32);
            bf16x8 b1 = *(const bf16x8*)(bb + (16 + ln) * 32);
            acc0 = __builtin_amdgcn_mfma_f32_16x16x32_bf16(aj, b0, acc0, 0, 0, 0);
            acc1 = __builtin_amdgcn_mfma_f32_16x16x32_bf16(aj, b1, acc1, 0, 0, 0);
        }
        if (grp) {  // + A_static @ x3 (unit scale)
            const __bf16* bb = &Bmats[16 * 1024 + kq * 8];
            bf16x8 b0 = *(const bf16x8*)(bb + ln * 32);
            bf16x8 b1 = *(const bf16x8*)(bb + (16 + ln) * 32);
            acc0 = __builtin_amdgcn_mfma_f32_16x16x32_bf16(araw, b0, acc0, 0, 0, 0);
            acc1 = __builtin_amdgcn_mfma_f32_16x16x32_bf16(araw, b1, acc1, 0, 0, 0);
        }
        float* dstArr = grp ? gcnp : xatt;
        #pragma unroll
        for (int r = 0; r < 4; ++r) {
            int row = mt * 16 + kq * 4 + r;
            float bias = grp ? (alpha * edge_b[row] * S3s[row])
                             : (att_b[row] * S3s[row]);
            dstArr[row * 25 + ln] = acc0[r] + bias;
            if (ln < 9) dstArr[row * 25 + 16 + ln] = acc1[r] + bias;
        }
    }
    __syncthreads();

    // ===== MLP stage A: xm[c] = mean_v xatt[c][v], 4 lanes per c =====
    if (t < 256) {
        int cq = t >> 2, s = t & 3;
        float p = 0.0f;
        #pragma unroll 1
        for (int v = s; v < 25; v += 4) p += xatt[cq * 25 + v];
        p += __shfl_down(p, 2, 4);
        p += __shfl_down(p, 1, 4);
        if (s == 0) xmean[cq] = p * 0.04f;
    }
    __syncthreads();

    // ===== MLP stage B: h[i] = GELU(BN(cc1 @ xm)), 8 lanes per i =====
    if (t < 256) {
        int i = t >> 3, s = t & 7;
        float p = 0.0f;
        #pragma unroll
        for (int k = 0; k < 8; ++k)
            p += cc1_w[i * 64 + s + 8 * k] * xmean[s + 8 * k];
        p += __shfl_down(p, 4, 8);
        p += __shfl_down(p, 2, 8);
        p += __shfl_down(p, 1, 8);
        if (s == 0) {
            p += cc1_b[i];
            p = (p - bn_m[i]) * (bn_g[i] * rsqrtf(bn_v[i] + 1e-5f)) + bn_b[i];
            hbuf[i] = 0.5f * p * (1.0f + erff(p * 0.70710678118654752f));
        }
    }
    __syncthreads();

    // ===== MLP stage C: catt[c] = sigmoid(cc2 @ h), 4 lanes per c =====
    if (t < 256) {
        int cq = t >> 2, s = t & 3;
        float p = 0.0f;
        #pragma unroll
        for (int k = 0; k < 8; ++k)
            p += cc2_w[cq * 32 + s + 4 * k] * hbuf[s + 4 * k];
        p += __shfl_down(p, 2, 4);
        p += __shfl_down(p, 1, 4);
        if (s == 0) {
            float cv = fast_sigmoid(p + cc2_b[cq]);
            catt[cq] = cv;
            csct[cq] = cs_w[cq] * cv;
        }
    }
    __syncthreads();

    // ===== satt (t<200) overlapped with epilogue partials (all threads) =====
    float part[4];
    #pragma unroll
    for (int k = 0; k < 4; ++k) {
        int i = t + 512 * k;
        if (i < 1600) {
            int cc = i / 25;
            part[k] = gcnp[i] * catt[cc] + xv[k];
        }
    }
    if (t < 200) {
        int v = t >> 3, s8 = t & 7;
        float p = 0.0f;
        #pragma unroll
        for (int k = 0; k < 8; ++k) {
            int cc = s8 + 8 * k;
            p += csct[cc] * gcnp[cc * 25 + v];
        }
        p += __shfl_down(p, 4, 8);
        p += __shfl_down(p, 2, 8);
        p += __shfl_down(p, 1, 8);
        if (s8 == 0) satt[v] = fast_sigmoid(p + cs_b[0]);
    }
    __syncthreads();

    // ===== out = part + xatt*satt =====
    float* ob = out + (size_t)b * 1600;
    #pragma unroll
    for (int k = 0; k < 4; ++k) {
        int i = t + 512 * k;
        if (i < 1600) {
            int cc = i / 25, v = i - cc * 25;
            ob[i] = part[k] + xatt[i] * satt[v];
        }
    }
}

extern "C" void kernel_launch(void* const* d_in, const int* in_sizes, int n_in,
                              void* d_out, int out_size, void* d_ws, size_t ws_size,
                              hipStream_t stream) {
    const float* x        = (const float*)d_in[0];
    const float* A_static = (const float*)d_in[1];
    const float* w1       = (const float*)d_in[2];
    const float* b1       = (const float*)d_in[3];
    const float* w2       = (const float*)d_in[4];
    const float* b2       = (const float*)d_in[5];
    const float* w3       = (const float*)d_in[6];
    const float* b3       = (const float*)d_in[7];
    const float* diff_w   = (const float*)d_in[8];
    const float* diff_b   = (const float*)d_in[9];
    const float* edge_w   = (const float*)d_in[10];
    const float* edge_b   = (const float*)d_in[11];
    const float* att_w    = (const float*)d_in[12];
    const float* att_b    = (const float*)d_in[13];
    const float* cc1_w    = (const float*)d_in[14];
    const float* cc1_b    = (const float*)d_in[15];
    const float* bn_g     = (const float*)d_in[16];
    const float* bn_b     = (const float*)d_in[17];
    const float* bn_m     = (const float*)d_in[18];
    const float* bn_v     = (const float*)d_in[19];
    const float* cc2_w    = (const float*)d_in[20];
    const float* cc2_b    = (const float*)d_in[21];
    const float* cs_w     = (const float*)d_in[22];
    const float* cs_b     = (const float*)d_in[23];
    const float* alpha    = (const float*)d_in[24];
    float* outp = (float*)d_out;

    cga_fused<<<NB, 512, 0, stream>>>(x, A_static, w1, b1, w2, b2, w3, b3,
                                      diff_w, diff_b, edge_w, edge_b,
                                      att_w, att_b, cc1_w, cc1_b,
                                      bn_g, bn_b, bn_m, bn_v,
                                      cc2_w, cc2_b, cs_w, cs_b, alpha, outp);
}

// Round 12
// 19.571 us; speedup vs baseline: 3.4875x; 1.1097x over previous
//
#include <hip/hip_runtime.h>
#include <math.h>

#define NB   512

typedef __attribute__((ext_vector_type(8))) __bf16 bf16x8;
typedef __attribute__((ext_vector_type(4))) float  f32x4;

__device__ __forceinline__ float fast_rcp(float x) { return __builtin_amdgcn_rcpf(x); }
__device__ __forceinline__ float fast_tanh(float x) {
    float e = __expf(2.0f * x);
    return 1.0f - 2.0f * fast_rcp(e + 1.0f);
}
__device__ __forceinline__ float fast_sigmoid(float x) {
    return fast_rcp(1.0f + __expf(-x));
}
__device__ __forceinline__ unsigned pack_bf16(float a, float b) {
    unsigned short ux = __builtin_bit_cast(unsigned short, (__bf16)a);
    unsigned short uy = __builtin_bit_cast(unsigned short, (__bf16)b);
    return (unsigned)ux | ((unsigned)uy << 16);
}
__device__ __forceinline__ float bf16_res(float v) {   // v - bf16(v)
    return v - (float)(__bf16)v;
}

__global__ __launch_bounds__(512, 4)
void cga_fused(const float* __restrict__ x,
               const float* __restrict__ A_static,
               const float* __restrict__ w1, const float* __restrict__ b1,
               const float* __restrict__ w2, const float* __restrict__ b2,
               const float* __restrict__ w3, const float* __restrict__ b3,
               const float* __restrict__ diff_w, const float* __restrict__ diff_b,
               const float* __restrict__ edge_w, const float* __restrict__ edge_b,
               const float* __restrict__ att_w, const float* __restrict__ att_b,
               const float* __restrict__ cc1_w, const float* __restrict__ cc1_b,
               const float* __restrict__ bn_g, const float* __restrict__ bn_b,
               const float* __restrict__ bn_m, const float* __restrict__ bn_v,
               const float* __restrict__ cc2_w, const float* __restrict__ cc2_b,
               const float* __restrict__ cs_w, const float* __restrict__ cs_b,
               const float* __restrict__ alpha_p,
               float* __restrict__ out)
{
    const int b = blockIdx.x;
    const int t = threadIdx.x;
    const int c = t & 63;   // lane
    const int w = t >> 6;   // wave 0..7

    // Bmats: j=0..7 Q_m as B[n=v][k=u]; j=8..15 P_m as B[n=u][k=v]; j=16 A_static [n=u][k=v].
    // Before P2, Bmats elems [0..5119] alias wA hi [80][64] (XOR-swizzled fragments),
    // [5120..10239] wA lo. A_static block (elems 16384..) untouched by staging.
    __shared__ __align__(16) __bf16 Bmats[17 * 32 * 32];   // 34816 B
    __shared__ __align__(16) __bf16 x3bf[64 * 32];         // A-operand of A/B phase [c][k=v]
    __shared__ __align__(16) __bf16 xT[2 * 32 * 72];       // x^T hi/lo planes [v][cin], stride 72
    __shared__ float x1s[200], x2s[200];
    __shared__ float xatt[1600], gcnp[1600];
    __shared__ float att_wT[512], edge_wT[512];            // [j][c], edge pre-scaled by alpha
    __shared__ float S3s[64], catt[64], satt[32];
    __shared__ float xmean[64], hbuf[32], csct[64];

    const float alpha = alpha_p[0];
    const float* xb = x + (size_t)b * 1600;
    __bf16* const xThi = xT;
    __bf16* const xTlo = xT + 32 * 72;

    // ===== x preload into registers (reused by staging AND epilogue) =====
    float xv[4];
    xv[0] = xb[t]; xv[1] = xb[t + 512]; xv[2] = xb[t + 1024];
    xv[3] = (t < 64) ? xb[t + 1536] : 0.0f;

    // ===== stage: x -> transposed hi/lo, wA hi/lo (swizzled), misc =====
    {
        #pragma unroll
        for (int k = 0; k < 4; ++k) {
            int i = t + 512 * k;
            if (i < 1600) {
                int cin = i / 25, v = i - cin * 25;
                float f = xv[k];
                __bf16 h = (__bf16)f;
                xThi[v * 72 + cin] = h;
                xTlo[v * 72 + cin] = (__bf16)(f - (float)h);
            }
        }
        #pragma unroll 1
        for (int i = t; i < 1008; i += 512) {           // zero pad rows v=25..31, both planes
            int p = (i >= 504), r = i - p * 504;
            (p ? xTlo : xThi)[25 * 72 + r] = (__bf16)0.f;
        }
        // wA fragments, XOR-swizzled: dword sw = i ^ (((i>>5)&7)<<2)
        unsigned* wA32   = (unsigned*)Bmats;
        unsigned* wAlo32 = wA32 + 2560;
        #pragma unroll 1
        for (int i = t; i < 2048; i += 512) {
            float2 wv = *(const float2*)&w3[2 * i];
            int sw = i ^ (((i >> 5) & 7) << 2);
            wA32[sw]   = pack_bf16(wv.x, wv.y);
            wAlo32[sw] = pack_bf16(bf16_res(wv.x), bf16_res(wv.y));
        }
        {   // w1 -> rows 64-71, w2 -> rows 72-79 (256 u32 each)
            int which = t >> 8, j = t & 255;
            const float* wsrc = which ? w2 : w1;
            float2 wv = *(const float2*)&wsrc[2 * j];
            int i2 = 2048 + t;
            int sw = i2 ^ (((i2 >> 5) & 7) << 2);
            wA32[sw]   = pack_bf16(wv.x, wv.y);
            wAlo32[sw] = pack_bf16(bf16_res(wv.x), bf16_res(wv.y));
        }
        unsigned* x3b32 = (unsigned*)x3bf;
        #pragma unroll 1
        for (int i = t; i < 1024; i += 512) x3b32[i] = 0u;
        {   // att_wT[j][c], edge_wT[j][c] (alpha folded)
            int j = t >> 6;
            att_wT [j * 64 + c] = att_w [c * 8 + j];
            edge_wT[j * 64 + c] = alpha * edge_w[c * 8 + j];
        }
        {   // A_static -> Bmats[16][n=u][k=v], zero-padded
            int n = t >> 4, p = t & 15;
            int k0 = 2 * p, k1 = k0 + 1;
            float a0 = (n < 25 && k0 < 25) ? A_static[n * 25 + k0] : 0.0f;
            float a1 = (n < 25 && k1 < 25) ? A_static[n * 25 + k1] : 0.0f;
            ((unsigned*)Bmats)[16 * 512 + n * 16 + p] = pack_bf16(a0, a1);
        }
    }
    __syncthreads();

    // ===== P1 (split-bf16 MFMA): [x3; x1; x2] = wA(80x64) @ x(64x25) =====
    {
        const int ln = c & 15, kq = c >> 4;
        #pragma unroll 1
        for (int pass = 0; pass < 2; ++pass) {
            const int jb = pass ? (w + 8) : w;
            if (jb <= 9) {
                const int nt = (jb >= 5) ? 1 : 0;
                const int mt = jb - nt * 5;
                const int arow = mt * 16 + ln;
                const int brow = nt * 16 + ln;
                const int r7 = arow & 7;
                const __bf16* hiB = Bmats        + arow * 64;
                const __bf16* loB = Bmats + 5120 + arow * 64;
                f32x4 acc = {0.f, 0.f, 0.f, 0.f};
                bf16x8 ah0 = *(const bf16x8*)(hiB + (((kq    ) ^ r7) << 3));
                bf16x8 ah1 = *(const bf16x8*)(hiB + (((kq + 4) ^ r7) << 3));
                bf16x8 al0 = *(const bf16x8*)(loB + (((kq    ) ^ r7) << 3));
                bf16x8 al1 = *(const bf16x8*)(loB + (((kq + 4) ^ r7) << 3));
                bf16x8 bh0 = *(const bf16x8*)&xThi[brow * 72 + kq * 8];
                bf16x8 bh1 = *(const bf16x8*)&xThi[brow * 72 + 32 + kq * 8];
                bf16x8 bl0 = *(const bf16x8*)&xTlo[brow * 72 + kq * 8];
                bf16x8 bl1 = *(const bf16x8*)&xTlo[brow * 72 + 32 + kq * 8];
                acc = __builtin_amdgcn_mfma_f32_16x16x32_bf16(ah0, bh0, acc, 0, 0, 0);
                acc = __builtin_amdgcn_mfma_f32_16x16x32_bf16(ah1, bh1, acc, 0, 0, 0);
                acc = __builtin_amdgcn_mfma_f32_16x16x32_bf16(ah0, bl0, acc, 0, 0, 0);
                acc = __builtin_amdgcn_mfma_f32_16x16x32_bf16(ah1, bl1, acc, 0, 0, 0);
                acc = __builtin_amdgcn_mfma_f32_16x16x32_bf16(al0, bh0, acc, 0, 0, 0);
                acc = __builtin_amdgcn_mfma_f32_16x16x32_bf16(al1, bh1, acc, 0, 0, 0);
                const int colv = nt * 16 + ln;
                if (colv < 25) {
                    if (mt < 4) {
                        #pragma unroll
                        for (int r = 0; r < 4; ++r) {
                            int cc = mt * 16 + kq * 4 + r;
                            float val = acc[r] + b3[cc];
                            x3bf[cc * 32 + colv] = (__bf16)val;
                        }
                    } else {
                        #pragma unroll
                        for (int r = 0; r < 4; ++r) {
                            int row16 = kq * 4 + r;
                            int which = row16 >> 3, m = row16 & 7;
                            float val = acc[r] + (which ? b2[m] : b1[m]);
                            (which ? x2s : x1s)[m * 25 + colv] = val;
                        }
                    }
                }
            }
        }
    }
    __syncthreads();

    // ===== P2 (merged Q+P, packed writes): 4096 iters cover both banks =====
    #pragma unroll 1
    for (int i = t; i < 4096; i += 512) {
        int m  = i >> 9;            // 0..7
        int r  = i & 511;
        int a  = r >> 4;            // row 0..31
        int bp = r & 15;            // col pair: cols 2bp, 2bp+1
        int v0 = 2 * bp, v1 = v0 + 1;
        float q0 = 0.f, q1 = 0.f, p0 = 0.f, p1 = 0.f;
        if (a < 25) {
            // Q: row=v=a, cols=u
            float x2a = x2s[m * 25 + a] * 0.2f;
            if (v0 < 25) q0 = fast_tanh(x1s[m * 25 + v0] * x2a);
            if (v1 < 25) q1 = fast_tanh(x1s[m * 25 + v1] * x2a);
            // P: row=u=a, cols=v; shared per-row term t0
            float dw0 = diff_w[2 * m], dw1 = diff_w[2 * m + 1];
            const float* rowA; const float* colA; int j0;
            if (m < 4) { j0 = 2 * m;     rowA = x1s; colA = x2s; }
            else       { j0 = 2 * m - 8; rowA = x2s; colA = x1s; }
            float t0 = dw0 * rowA[j0 * 25 + a] + dw1 * rowA[(j0 + 1) * 25 + a] + diff_b[m];
            if (v0 < 25) p0 = fast_tanh(t0 - dw0 * colA[j0 * 25 + v0] - dw1 * colA[(j0 + 1) * 25 + v0]);
            if (v1 < 25) p1 = fast_tanh(t0 - dw0 * colA[j0 * 25 + v1] - dw1 * colA[(j0 + 1) * 25 + v1]);
        }
        ((unsigned*)Bmats)[(m * 32 + a) * 16 + bp]       = pack_bf16(q0, q1);
        ((unsigned*)Bmats)[((8 + m) * 32 + a) * 16 + bp] = pack_bf16(p0, p1);
    }
    if (t < 64) {               // S3 from zero-padded bf16 x3 row (vector reads)
        const bf16x8* xr = (const bf16x8*)&x3bf[t * 32];
        float s = 0.0f;
        #pragma unroll
        for (int q = 0; q < 4; ++q) {
            bf16x8 vq = xr[q];
            #pragma unroll
            for (int e = 0; e < 8; ++e) s += (float)vq[e];
        }
        S3s[t] = s;
    }
    __syncthreads();

    // ===== A/B MFMA: waves 0-3 -> xatt (j 0..7), waves 4-7 -> gcnp (j 8..16) =====
    {
        const int ln = c & 15, kq = c >> 4;
        const int grp = w >> 2;
        const int mt  = w & 3;
        const int arow = mt * 16 + ln;

        const bf16x8 araw = *(const bf16x8*)&x3bf[arow * 32 + kq * 8];
        float av[8];
        #pragma unroll
        for (int e = 0; e < 8; ++e) av[e] = (float)araw[e];

        f32x4 acc0 = {0.f, 0.f, 0.f, 0.f};
        f32x4 acc1 = {0.f, 0.f, 0.f, 0.f};
        const float* scT = grp ? edge_wT : att_wT;
        const int jbase = grp ? 8 : 0;

        #pragma unroll
        for (int j = 0; j < 8; ++j) {
            float sj = scT[j * 64 + arow];
            bf16x8 aj;
            #pragma unroll
            for (int e = 0; e < 8; ++e) aj[e] = (__bf16)(av[e] * sj);
            const __bf16* bb = &Bmats[(jbase + j) * 1024 + kq * 8];
            bf16x8 b0 = *(const bf16x8*)(bb + ln * 32);
            bf16x8 b1 = *(const bf16x8*)(bb + (16 + ln) * 32);
            acc0 = __builtin_amdgcn_mfma_f32_16x16x32_bf16(aj, b0, acc0, 0, 0, 0);
            acc1 = __builtin_amdgcn_mfma_f32_16x16x32_bf16(aj, b1, acc1, 0, 0, 0);
        }
        if (grp) {  // + A_static @ x3 (unit scale)
            const __bf16* bb = &Bmats[16 * 1024 + kq * 8];
            bf16x8 b0 = *(const bf16x8*)(bb + ln * 32);
            bf16x8 b1 = *(const bf16x8*)(bb + (16 + ln) * 32);
            acc0 = __builtin_amdgcn_mfma_f32_16x16x32_bf16(araw, b0, acc0, 0, 0, 0);
            acc1 = __builtin_amdgcn_mfma_f32_16x16x32_bf16(araw, b1, acc1, 0, 0, 0);
        }
        float* dstArr = grp ? gcnp : xatt;
        #pragma unroll
        for (int r = 0; r < 4; ++r) {
            int row = mt * 16 + kq * 4 + r;
            float bias = grp ? (alpha * edge_b[row] * S3s[row])
                             : (att_b[row] * S3s[row]);
            dstArr[row * 25 + ln] = acc0[r] + bias;
            if (ln < 9) dstArr[row * 25 + 16 + ln] = acc1[r] + bias;
            if (!grp) {   // fold xmean: row-sum from accumulator registers
                float s = acc0[r] + ((ln < 9) ? acc1[r] : 0.0f);
                s += __shfl_xor(s, 1, 16);
                s += __shfl_xor(s, 2, 16);
                s += __shfl_xor(s, 4, 16);
                s += __shfl_xor(s, 8, 16);
                if (ln == 0) xmean[row] = (s + 25.0f * bias) * 0.04f;
            }
        }
    }
    __syncthreads();

    // ===== MLP stage B: h[i] = GELU(BN(cc1 @ xm)), 8 lanes per i =====
    if (t < 256) {
        int i = t >> 3, s = t & 7;
        float p = 0.0f;
        #pragma unroll
        for (int k = 0; k < 8; ++k)
            p += cc1_w[i * 64 + s + 8 * k] * xmean[s + 8 * k];
        p += __shfl_down(p, 4, 8);
        p += __shfl_down(p, 2, 8);
        p += __shfl_down(p, 1, 8);
        if (s == 0) {
            p += cc1_b[i];
            p = (p - bn_m[i]) * (bn_g[i] * rsqrtf(bn_v[i] + 1e-5f)) + bn_b[i];
            hbuf[i] = 0.5f * p * (1.0f + erff(p * 0.70710678118654752f));
        }
    }
    __syncthreads();

    // ===== MLP stage C: catt[c] = sigmoid(cc2 @ h), 4 lanes per c =====
    if (t < 256) {
        int cq = t >> 2, s = t & 3;
        float p = 0.0f;
        #pragma unroll
        for (int k = 0; k < 8; ++k)
            p += cc2_w[cq * 32 + s + 4 * k] * hbuf[s + 4 * k];
        p += __shfl_down(p, 2, 4);
        p += __shfl_down(p, 1, 4);
        if (s == 0) {
            float cv = fast_sigmoid(p + cc2_b[cq]);
            catt[cq] = cv;
            csct[cq] = cs_w[cq] * cv;
        }
    }
    __syncthreads();

    // ===== satt (t<200) overlapped with epilogue partials (all threads) =====
    float part[4];
    #pragma unroll
    for (int k = 0; k < 4; ++k) {
        int i = t + 512 * k;
        if (i < 1600) {
            int cc = i / 25;
            part[k] = gcnp[i] * catt[cc] + xv[k];
        }
    }
    if (t < 200) {
        int v = t >> 3, s8 = t & 7;
        float p = 0.0f;
        #pragma unroll
        for (int k = 0; k < 8; ++k) {
            int cc = s8 + 8 * k;
            p += csct[cc] * gcnp[cc * 25 + v];
        }
        p += __shfl_down(p, 4, 8);
        p += __shfl_down(p, 2, 8);
        p += __shfl_down(p, 1, 8);
        if (s8 == 0) satt[v] = fast_sigmoid(p + cs_b[0]);
    }
    __syncthreads();

    // ===== out = part + xatt*satt =====
    float* ob = out + (size_t)b * 1600;
    #pragma unroll
    for (int k = 0; k < 4; ++k) {
        int i = t + 512 * k;
        if (i < 1600) {
            int cc = i / 25, v = i - cc * 25;
            ob[i] = part[k] + xatt[i] * satt[v];
        }
    }
}

extern "C" void kernel_launch(void* const* d_in, const int* in_sizes, int n_in,
                              void* d_out, int out_size, void* d_ws, size_t ws_size,
                              hipStream_t stream) {
    const float* x        = (const float*)d_in[0];
    const float* A_static = (const float*)d_in[1];
    const float* w1       = (const float*)d_in[2];
    const float* b1       = (const float*)d_in[3];
    const float* w2       = (const float*)d_in[4];
    const float* b2       = (const float*)d_in[5];
    const float* w3       = (const float*)d_in[6];
    const float* b3       = (const float*)d_in[7];
    const float* diff_w   = (const float*)d_in[8];
    const float* diff_b   = (const float*)d_in[9];
    const float* edge_w   = (const float*)d_in[10];
    const float* edge_b   = (const float*)d_in[11];
    const float* att_w    = (const float*)d_in[12];
    const float* att_b    = (const float*)d_in[13];
    const float* cc1_w    = (const float*)d_in[14];
    const float* cc1_b    = (const float*)d_in[15];
    const float* bn_g     = (const float*)d_in[16];
    const float* bn_b     = (const float*)d_in[17];
    const float* bn_m     = (const float*)d_in[18];
    const float* bn_v     = (const float*)d_in[19];
    const float* cc2_w    = (const float*)d_in[20];
    const float* cc2_b    = (const float*)d_in[21];
    const float* cs_w     = (const float*)d_in[22];
    const float* cs_b     = (const float*)d_in[23];
    const float* alpha    = (const float*)d_in[24];
    float* outp = (float*)d_out;

    cga_fused<<<NB, 512, 0, stream>>>(x, A_static, w1, b1, w2, b2, w3, b3,
                                      diff_w, diff_b, edge_w, edge_b,
                                      att_w, att_b, cc1_w, cc1_b,
                                      bn_g, bn_b, bn_m, bn_v,
                                      cc2_w, cc2_b, cs_w, cs_b, alpha, outp);
}